// Round 2
// baseline (13199.777 us; speedup 1.0000x reference)
//
#include <hip/hip_runtime.h>
#include <hip/hip_bf16.h>

#define BSZ 16
#define SEQ 512
#define DIM 512
#define NH 8
#define DK 64
#define NROWS (BSZ*SEQ)   // 8192
#define DFF2 2048

// ---- GEMM: C[M,N] = A[M,K] @ W[K,N] (+ bias)(+ C if accum), opt relu. All fp32. ----
// 64x64 tile, K-step 16, 256 threads, each thread 4x4 outputs.
__global__ __launch_bounds__(256) void gemm_bias(
    const float* __restrict__ A, const float* __restrict__ W,
    const float* __restrict__ bias, float* __restrict__ C,
    int K, int lda, int ldw, int ldc, int relu, int accum)
{
    __shared__ float As[16][68];
    __shared__ float Bs[16][68];
    int tid = threadIdx.x;
    int tx = tid & 15, ty = tid >> 4;
    int n0 = blockIdx.x * 64, m0 = blockIdx.y * 64;
    int lmA = tid >> 2, lkA = (tid & 3) << 2;       // A: 64 rows x 16 k, float4/thread
    int lkB = tid >> 4, lnB = (tid & 15) << 2;      // W: 16 k x 64 n, float4/thread
    float acc[4][4] = {};
    for (int k0 = 0; k0 < K; k0 += 16) {
        float4 a4 = *(const float4*)&A[(size_t)(m0 + lmA) * lda + k0 + lkA];
        float4 w4 = *(const float4*)&W[(size_t)(k0 + lkB) * ldw + n0 + lnB];
        __syncthreads();
        As[lkA + 0][lmA] = a4.x; As[lkA + 1][lmA] = a4.y;
        As[lkA + 2][lmA] = a4.z; As[lkA + 3][lmA] = a4.w;
        Bs[lkB][lnB + 0] = w4.x; Bs[lkB][lnB + 1] = w4.y;
        Bs[lkB][lnB + 2] = w4.z; Bs[lkB][lnB + 3] = w4.w;
        __syncthreads();
        #pragma unroll
        for (int kk = 0; kk < 16; kk++) {
            float a[4], b[4];
            #pragma unroll
            for (int i = 0; i < 4; i++) a[i] = As[kk][ty * 4 + i];
            #pragma unroll
            for (int j = 0; j < 4; j++) b[j] = Bs[kk][tx * 4 + j];
            #pragma unroll
            for (int i = 0; i < 4; i++)
                #pragma unroll
                for (int j = 0; j < 4; j++) acc[i][j] += a[i] * b[j];
        }
    }
    float bb[4] = {0.f, 0.f, 0.f, 0.f};
    if (bias) {
        #pragma unroll
        for (int j = 0; j < 4; j++) bb[j] = bias[n0 + tx * 4 + j];
    }
    #pragma unroll
    for (int i = 0; i < 4; i++) {
        size_t off = (size_t)(m0 + ty * 4 + i) * ldc + n0 + tx * 4;
        float4 o;
        o.x = acc[i][0] + bb[0]; o.y = acc[i][1] + bb[1];
        o.z = acc[i][2] + bb[2]; o.w = acc[i][3] + bb[3];
        if (accum) {
            float4 c0 = *(const float4*)&C[off];
            o.x += c0.x; o.y += c0.y; o.z += c0.z; o.w += c0.w;
        }
        if (relu) { o.x = fmaxf(o.x, 0.f); o.y = fmaxf(o.y, 0.f);
                    o.z = fmaxf(o.z, 0.f); o.w = fmaxf(o.w, 0.f); }
        *(float4*)&C[off] = o;
    }
}

// ---- router: gates = softmax(qlin @ wg), top-2 (stable), mean over s -> rmask[B,NH] ----
__global__ void init_rmask(float* __restrict__ rmask) {
    int t = threadIdx.x;   // 128 = B*NH
    rmask[t] = ((t & 7) < 2) ? 1.0f : 0.0f;
}

__global__ __launch_bounds__(256) void router_kernel(
    const float* __restrict__ qlin, const float* __restrict__ wg,
    float* __restrict__ rmask)
{
    __shared__ float s_wg[DIM * 6];
    for (int i = threadIdx.x; i < DIM * 6; i += 256) s_wg[i] = wg[i];
    __syncthreads();
    int row = blockIdx.x * 256 + threadIdx.x;   // < 8192
    const float* xr = qlin + (size_t)row * DIM;
    float lg[6] = {0, 0, 0, 0, 0, 0};
    for (int d = 0; d < DIM; d++) {
        float x = xr[d];
        #pragma unroll
        for (int r = 0; r < 6; r++) lg[r] += x * s_wg[d * 6 + r];
    }
    float m = lg[0];
    #pragma unroll
    for (int r = 1; r < 6; r++) m = fmaxf(m, lg[r]);
    float s = 0.f;
    #pragma unroll
    for (int r = 0; r < 6; r++) { lg[r] = __expf(lg[r] - m); s += lg[r]; }
    float inv = 1.0f / s;
    #pragma unroll
    for (int r = 0; r < 6; r++) lg[r] *= inv;
    // top-2, lowest index wins ties == jax.lax.top_k
    int i1 = 0; float v1 = lg[0];
    #pragma unroll
    for (int r = 1; r < 6; r++) if (lg[r] > v1) { v1 = lg[r]; i1 = r; }
    int i2 = -1; float v2 = -1.f;
    #pragma unroll
    for (int r = 0; r < 6; r++) if (r != i1 && lg[r] > v2) { v2 = lg[r]; i2 = r; }
    int b = row >> 9;   // /512
    atomicAdd(&rmask[b * 8 + 2 + i1], v1 * (1.0f / (float)SEQ));
    atomicAdd(&rmask[b * 8 + 2 + i2], v2 * (1.0f / (float)SEQ));
}

// ---- attention: one block per (b,h,q). K==Q (kq_same). ----
// mask_flag=1: allow j<=q ; 0: allow j<q. Row q==0: uniform 1/SEQ over ALL keys.
__global__ __launch_bounds__(256) void attn_kernel(
    const float* __restrict__ qlin, const float* __restrict__ vlin,
    const float* __restrict__ rmask, float* __restrict__ ctx, int mask_flag)
{
    __shared__ float s_sc[SEQ];
    __shared__ float s_q[DK];
    __shared__ float s_part[4][DK];
    __shared__ float red[4];
    int q = blockIdx.x, h = blockIdx.y, b = blockIdx.z;
    int tid = threadIdx.x;
    int lane = tid & 63, wid = tid >> 6;
    size_t baseQ = ((size_t)(b * SEQ + q) * DIM) + h * DK;
    if (tid < DK) s_q[tid] = qlin[baseQ + tid];
    __syncthreads();

    int jmax = mask_flag ? q : (q - 1);
    float scale;
    if (q == 0) {
        scale = 1.0f / (float)SEQ;
    } else {
        size_t rowBase = ((size_t)b * SEQ) * DIM + h * DK;
        for (int j = tid; j <= jmax; j += 256) {
            const float* kr = qlin + rowBase + (size_t)j * DIM;
            float sdot = 0.f;
            #pragma unroll
            for (int d = 0; d < DK; d++) sdot += s_q[d] * kr[d];
            s_sc[j] = sdot * 0.125f;   // 1/sqrt(64)
        }
        float lm = -1e30f;
        for (int j = tid; j <= jmax; j += 256) lm = fmaxf(lm, s_sc[j]);
        for (int o = 32; o > 0; o >>= 1) lm = fmaxf(lm, __shfl_down(lm, o, 64));
        if (lane == 0) red[wid] = lm;
        __syncthreads();
        float M = fmaxf(fmaxf(red[0], red[1]), fmaxf(red[2], red[3]));
        __syncthreads();
        float ls = 0.f;
        for (int j = tid; j <= jmax; j += 256) {
            float e = __expf(s_sc[j] - M);
            s_sc[j] = e;
            ls += e;
        }
        for (int o = 32; o > 0; o >>= 1) ls += __shfl_down(ls, o, 64);
        if (lane == 0) red[wid] = ls;
        __syncthreads();
        float SUM = red[0] + red[1] + red[2] + red[3];
        scale = 1.0f / SUM;
    }

    int d = lane, chunk = wid;
    float acc = 0.f;
    size_t vBase = ((size_t)b * SEQ) * DIM + h * DK + d;
    if (q == 0) {
        for (int j = chunk; j < SEQ; j += 4) acc += vlin[vBase + (size_t)j * DIM];
    } else {
        for (int j = chunk; j <= jmax; j += 4) acc += s_sc[j] * vlin[vBase + (size_t)j * DIM];
    }
    s_part[chunk][d] = acc;
    __syncthreads();
    if (wid == 0) {
        float tot = s_part[0][d] + s_part[1][d] + s_part[2][d] + s_part[3][d];
        ctx[baseQ + d] = tot * scale * rmask[b * 8 + h];
    }
}

// ---- x = LN(x + y) with per-layer gamma/beta (fp32) ----
__global__ __launch_bounds__(256) void add_ln(
    float* __restrict__ x, const float* __restrict__ y,
    const float* __restrict__ g, const float* __restrict__ bta)
{
    __shared__ float redA[4], redB[4];
    int row = blockIdx.x, tid = threadIdx.x;
    size_t base = (size_t)row * DIM;
    float t0 = x[base + tid] + y[base + tid];
    float t1 = x[base + tid + 256] + y[base + tid + 256];
    float s = t0 + t1, sq = t0 * t0 + t1 * t1;
    for (int o = 32; o > 0; o >>= 1) { s += __shfl_down(s, o, 64); sq += __shfl_down(sq, o, 64); }
    int lane = tid & 63, wid = tid >> 6;
    if (lane == 0) { redA[wid] = s; redB[wid] = sq; }
    __syncthreads();
    float S1 = redA[0] + redA[1] + redA[2] + redA[3];
    float S2 = redB[0] + redB[1] + redB[2] + redB[3];
    float mu = S1 * (1.0f / (float)DIM);
    float var = S2 * (1.0f / (float)DIM) - mu * mu;
    float rstd = rsqrtf(var + 1e-5f);
    x[base + tid]       = g[tid]       * (t0 - mu) * rstd + bta[tid];
    x[base + tid + 256] = g[tid + 256] * (t1 - mu) * rstd + bta[tid + 256];
}

// ---------------- host side ----------------
extern "C" void kernel_launch(void* const* d_in, const int* in_sizes, int n_in,
                              void* d_out, int out_size, void* d_ws, size_t ws_size,
                              hipStream_t stream) {
    const float* qe   = (const float*)d_in[0];
    const float* ie   = (const float*)d_in[1];
    const float* wq   = (const float*)d_in[2];
    const float* bq   = (const float*)d_in[3];
    const float* wv   = (const float*)d_in[4];
    const float* bv   = (const float*)d_in[5];
    const float* wo   = (const float*)d_in[6];
    const float* bo   = (const float*)d_in[7];
    const float* wg   = (const float*)d_in[8];
    const float* ln1g = (const float*)d_in[9];
    const float* ln1b = (const float*)d_in[10];
    const float* fw1  = (const float*)d_in[11];
    const float* fb1  = (const float*)d_in[12];
    const float* fw2  = (const float*)d_in[13];
    const float* fb2  = (const float*)d_in[14];
    const float* ln2g = (const float*)d_in[15];
    const float* ln2b = (const float*)d_in[16];

    const size_t RD = (size_t)NROWS * DIM;        // 4,194,304 floats
    float* ws    = (float*)d_ws;
    float* xbuf  = ws;                            // question stream (mutable)
    float* ybuf  = xbuf + RD;                     // knowledge stream (mutable)
    float* qlin  = ybuf + RD;
    float* vbuf  = qlin + RD;                     // v; reused as proj after attn
    float* ctxb  = vbuf + RD;
    float* hchk  = ctxb + RD;                     // FFN hidden, 512-col chunks
    float* rmask = hchk + RD;                     // 128 floats
    float* proj  = vbuf;                          // alias: vbuf dead after attn

    const size_t nBytes = RD * sizeof(float);
    hipMemcpyAsync(xbuf, qe, nBytes, hipMemcpyDeviceToDevice, stream);
    hipMemcpyAsync(ybuf, ie, nBytes, hipMemcpyDeviceToDevice, stream);

    auto run_gemm = [&](const float* A, const float* W, const float* bias, float* C,
                        int M, int N, int K, int lda, int ldw, int ldc, int relu, int accum) {
        dim3 g(N / 64, M / 64);
        gemm_bias<<<g, 256, 0, stream>>>(A, W, bias, C, K, lda, ldw, ldc, relu, accum);
    };

    auto run_block = [&](float* xq, const float* xv, int l, int maskf, int pos) {
        run_gemm(xq, wq + (size_t)l * DIM * DIM, bq + (size_t)l * DIM, qlin,
                 NROWS, DIM, DIM, DIM, DIM, DIM, 0, 0);
        run_gemm(xv, wv + (size_t)l * DIM * DIM, bv + (size_t)l * DIM, vbuf,
                 NROWS, DIM, DIM, DIM, DIM, DIM, 0, 0);
        init_rmask<<<1, 128, 0, stream>>>(rmask);
        router_kernel<<<NROWS / 256, 256, 0, stream>>>(qlin, wg + (size_t)l * DIM * 6, rmask);
        attn_kernel<<<dim3(SEQ, NH, BSZ), 256, 0, stream>>>(qlin, vbuf, rmask, ctxb, maskf);
        run_gemm(ctxb, wo + (size_t)l * DIM * DIM, bo + (size_t)l * DIM, proj,
                 NROWS, DIM, DIM, DIM, DIM, DIM, 0, 0);
        add_ln<<<NROWS, 256, 0, stream>>>(xq, proj, ln1g + (size_t)l * DIM, ln1b + (size_t)l * DIM);
        if (pos) {
            // FFN in 4 chunks of 512 hidden cols to bound workspace
            for (int c = 0; c < 4; c++) {
                run_gemm(xq, fw1 + (size_t)l * DIM * DFF2 + c * 512,
                         fb1 + (size_t)l * DFF2 + c * 512, hchk,
                         NROWS, 512, DIM, DIM, DFF2, 512, 1, 0);
                run_gemm(hchk, fw2 + (size_t)l * DFF2 * DIM + (size_t)c * 512 * DIM,
                         (c == 0) ? (fb2 + (size_t)l * DIM) : nullptr, proj,
                         NROWS, DIM, 512, 512, DIM, DIM, 0, (c == 0) ? 0 : 1);
            }
            add_ln<<<NROWS, 256, 0, stream>>>(xq, proj, ln2g + (size_t)l * DIM, ln2b + (size_t)l * DIM);
        }
    };

    // knowledge encoder
    run_block(ybuf, ybuf, 0, 1, 0);
    run_block(ybuf, ybuf, 1, 1, 0);
    // question encoder, alternating
    run_block(xbuf, xbuf, 2, 1, 0);
    run_block(xbuf, ybuf, 3, 0, 1);
    run_block(xbuf, xbuf, 4, 1, 0);
    run_block(xbuf, ybuf, 5, 0, 1);

    hipMemcpyAsync(d_out, xbuf, nBytes, hipMemcpyDeviceToDevice, stream);
}

// Round 3
// 3891.785 us; speedup vs baseline: 3.3917x; 3.3917x over previous
//
#include <hip/hip_runtime.h>
#include <hip/hip_bf16.h>

#define BSZ 16
#define SEQ 512
#define DIM 512
#define NH 8
#define DK 64
#define NROWS (BSZ*SEQ)   // 8192
#define DFF2 2048

// ---- GEMM: C[M,N] = A[M,K] @ W[K,N] (+ bias)(+ C if accum), opt relu. All fp32. ----
__global__ __launch_bounds__(256) void gemm_bias(
    const float* __restrict__ A, const float* __restrict__ W,
    const float* __restrict__ bias, float* __restrict__ C,
    int K, int lda, int ldw, int ldc, int relu, int accum)
{
    __shared__ float As[16][68];
    __shared__ float Bs[16][68];
    int tid = threadIdx.x;
    int tx = tid & 15, ty = tid >> 4;
    int n0 = blockIdx.x * 64, m0 = blockIdx.y * 64;
    int lmA = tid >> 2, lkA = (tid & 3) << 2;
    int lkB = tid >> 4, lnB = (tid & 15) << 2;
    float acc[4][4] = {};
    for (int k0 = 0; k0 < K; k0 += 16) {
        float4 a4 = *(const float4*)&A[(size_t)(m0 + lmA) * lda + k0 + lkA];
        float4 w4 = *(const float4*)&W[(size_t)(k0 + lkB) * ldw + n0 + lnB];
        __syncthreads();
        As[lkA + 0][lmA] = a4.x; As[lkA + 1][lmA] = a4.y;
        As[lkA + 2][lmA] = a4.z; As[lkA + 3][lmA] = a4.w;
        Bs[lkB][lnB + 0] = w4.x; Bs[lkB][lnB + 1] = w4.y;
        Bs[lkB][lnB + 2] = w4.z; Bs[lkB][lnB + 3] = w4.w;
        __syncthreads();
        #pragma unroll
        for (int kk = 0; kk < 16; kk++) {
            float a[4], b[4];
            #pragma unroll
            for (int i = 0; i < 4; i++) a[i] = As[kk][ty * 4 + i];
            #pragma unroll
            for (int j = 0; j < 4; j++) b[j] = Bs[kk][tx * 4 + j];
            #pragma unroll
            for (int i = 0; i < 4; i++)
                #pragma unroll
                for (int j = 0; j < 4; j++) acc[i][j] += a[i] * b[j];
        }
    }
    float bb[4] = {0.f, 0.f, 0.f, 0.f};
    if (bias) {
        #pragma unroll
        for (int j = 0; j < 4; j++) bb[j] = bias[n0 + tx * 4 + j];
    }
    #pragma unroll
    for (int i = 0; i < 4; i++) {
        size_t off = (size_t)(m0 + ty * 4 + i) * ldc + n0 + tx * 4;
        float4 o;
        o.x = acc[i][0] + bb[0]; o.y = acc[i][1] + bb[1];
        o.z = acc[i][2] + bb[2]; o.w = acc[i][3] + bb[3];
        if (accum) {
            float4 c0 = *(const float4*)&C[off];
            o.x += c0.x; o.y += c0.y; o.z += c0.z; o.w += c0.w;
        }
        if (relu) { o.x = fmaxf(o.x, 0.f); o.y = fmaxf(o.y, 0.f);
                    o.z = fmaxf(o.z, 0.f); o.w = fmaxf(o.w, 0.f); }
        *(float4*)&C[off] = o;
    }
}

// ---- router ----
__global__ void init_rmask(float* __restrict__ rmask) {
    int t = threadIdx.x;   // 128 = B*NH
    rmask[t] = ((t & 7) < 2) ? 1.0f : 0.0f;
}

__global__ __launch_bounds__(256) void router_kernel(
    const float* __restrict__ qlin, const float* __restrict__ wg,
    float* __restrict__ rmask)
{
    __shared__ float s_wg[DIM * 6];
    for (int i = threadIdx.x; i < DIM * 6; i += 256) s_wg[i] = wg[i];
    __syncthreads();
    int row = blockIdx.x * 256 + threadIdx.x;
    const float* xr = qlin + (size_t)row * DIM;
    float lg[6] = {0, 0, 0, 0, 0, 0};
    for (int d = 0; d < DIM; d++) {
        float x = xr[d];
        #pragma unroll
        for (int r = 0; r < 6; r++) lg[r] += x * s_wg[d * 6 + r];
    }
    float m = lg[0];
    #pragma unroll
    for (int r = 1; r < 6; r++) m = fmaxf(m, lg[r]);
    float s = 0.f;
    #pragma unroll
    for (int r = 0; r < 6; r++) { lg[r] = __expf(lg[r] - m); s += lg[r]; }
    float inv = 1.0f / s;
    #pragma unroll
    for (int r = 0; r < 6; r++) lg[r] *= inv;
    int i1 = 0; float v1 = lg[0];
    #pragma unroll
    for (int r = 1; r < 6; r++) if (lg[r] > v1) { v1 = lg[r]; i1 = r; }
    int i2 = -1; float v2 = -1.f;
    #pragma unroll
    for (int r = 0; r < 6; r++) if (r != i1 && lg[r] > v2) { v2 = lg[r]; i2 = r; }
    int b = row >> 9;
    atomicAdd(&rmask[b * 8 + 2 + i1], v1 * (1.0f / (float)SEQ));
    atomicAdd(&rmask[b * 8 + 2 + i2], v2 * (1.0f / (float)SEQ));
}

// ---- flash attention: block per (qtile=64 rows, h, b). kq_same: K comes from qlin. ----
// mask_flag=1: j<=q ; 0: j<q. Row q==0 written garbage here, fixed by attn_row0.
__global__ __launch_bounds__(256) void attn_flash(
    const float* __restrict__ qlin, const float* __restrict__ vlin,
    const float* __restrict__ rmask, float* __restrict__ ctx, int mask_flag)
{
    __shared__ float s_q [64][68];
    __shared__ float s_kp[64][68];   // K^T during QK, then P
    __shared__ float s_v [64][68];
    int qt = blockIdx.x, h = blockIdx.y, b = blockIdx.z;
    int tid = threadIdx.x;
    int lane = tid & 63;
    int wid = tid >> 6;
    int r  = wid * 16 + (lane >> 2);   // local q-row this thread owns
    int c0 = (lane & 3) * 16;          // 16-col/dim segment this thread owns
    int lr = tid >> 2, lc = (tid & 3) * 16;   // staging: row lr, cols lc..lc+15
    int qglob = qt * 64 + r;

    // load Q tile
    {
        const float* src = qlin + ((size_t)(b * SEQ + qt * 64 + lr) * DIM) + h * DK + lc;
        float4 q0 = ((const float4*)src)[0], q1 = ((const float4*)src)[1];
        float4 q2 = ((const float4*)src)[2], q3 = ((const float4*)src)[3];
        *(float4*)&s_q[lr][lc]      = q0; *(float4*)&s_q[lr][lc + 4]  = q1;
        *(float4*)&s_q[lr][lc + 8]  = q2; *(float4*)&s_q[lr][lc + 12] = q3;
    }

    float o[16];
    #pragma unroll
    for (int i = 0; i < 16; i++) o[i] = 0.f;
    float m = -1e30f, l = 0.f;

    for (int jt = 0; jt <= qt; jt++) {
        // stage K (transposed) and V tiles
        const float* ksrc = qlin + ((size_t)(b * SEQ + jt * 64 + lr) * DIM) + h * DK + lc;
        const float* vsrc = vlin + ((size_t)(b * SEQ + jt * 64 + lr) * DIM) + h * DK + lc;
        float4 k0 = ((const float4*)ksrc)[0], k1 = ((const float4*)ksrc)[1];
        float4 k2 = ((const float4*)ksrc)[2], k3 = ((const float4*)ksrc)[3];
        float4 v0 = ((const float4*)vsrc)[0], v1 = ((const float4*)vsrc)[1];
        float4 v2 = ((const float4*)vsrc)[2], v3 = ((const float4*)vsrc)[3];
        __syncthreads();   // previous iteration's PV reads complete
        float kk[16] = {k0.x,k0.y,k0.z,k0.w, k1.x,k1.y,k1.z,k1.w,
                        k2.x,k2.y,k2.z,k2.w, k3.x,k3.y,k3.z,k3.w};
        #pragma unroll
        for (int i = 0; i < 16; i++) s_kp[lc + i][lr] = kk[i];
        *(float4*)&s_v[lr][lc]      = v0; *(float4*)&s_v[lr][lc + 4]  = v1;
        *(float4*)&s_v[lr][lc + 8]  = v2; *(float4*)&s_v[lr][lc + 12] = v3;
        __syncthreads();   // staging visible (also covers s_q on first iter)

        // QK^T: 16 scores per thread (row r, cols jt*64+c0..+15)
        float sc[16];
        #pragma unroll
        for (int i = 0; i < 16; i++) sc[i] = 0.f;
        for (int d = 0; d < 64; d++) {
            float qv = s_q[r][d];
            const float4* kr = (const float4*)&s_kp[d][c0];
            float4 a = kr[0], bq = kr[1], c = kr[2], e = kr[3];
            sc[0]  += qv * a.x;  sc[1]  += qv * a.y;  sc[2]  += qv * a.z;  sc[3]  += qv * a.w;
            sc[4]  += qv * bq.x; sc[5]  += qv * bq.y; sc[6]  += qv * bq.z; sc[7]  += qv * bq.w;
            sc[8]  += qv * c.x;  sc[9]  += qv * c.y;  sc[10] += qv * c.z;  sc[11] += qv * c.w;
            sc[12] += qv * e.x;  sc[13] += qv * e.y;  sc[14] += qv * e.z;  sc[15] += qv * e.w;
        }
        // scale + mask (diagonal tile only)
        if (jt == qt) {
            int bound = mask_flag ? qglob : (qglob - 1);
            #pragma unroll
            for (int i = 0; i < 16; i++) {
                int jg = jt * 64 + c0 + i;
                sc[i] = (jg <= bound) ? sc[i] * 0.125f : -1e30f;
            }
        } else {
            #pragma unroll
            for (int i = 0; i < 16; i++) sc[i] *= 0.125f;
        }
        // online softmax update (row shared by 4 consecutive lanes)
        float tmax = sc[0];
        #pragma unroll
        for (int i = 1; i < 16; i++) tmax = fmaxf(tmax, sc[i]);
        tmax = fmaxf(tmax, __shfl_xor(tmax, 1));
        tmax = fmaxf(tmax, __shfl_xor(tmax, 2));
        float mnew = fmaxf(m, tmax);
        float alpha = __expf(m - mnew);
        float p[16], tsum = 0.f;
        #pragma unroll
        for (int i = 0; i < 16; i++) { p[i] = __expf(sc[i] - mnew); tsum += p[i]; }
        tsum += __shfl_xor(tsum, 1);
        tsum += __shfl_xor(tsum, 2);
        l = l * alpha + tsum;
        m = mnew;
        #pragma unroll
        for (int i = 0; i < 16; i++) o[i] *= alpha;
        __syncthreads();   // all QK reads of s_kp done
        #pragma unroll
        for (int i = 0; i < 16; i++) s_kp[r][c0 + i] = p[i];
        __syncthreads();   // P visible

        // PV: o[r][c0..+15] += sum_j P[r][j] * V[j][c0..+15]
        for (int j = 0; j < 64; j++) {
            float pv = s_kp[r][j];
            const float4* vr = (const float4*)&s_v[j][c0];
            float4 a = vr[0], bq = vr[1], c = vr[2], e = vr[3];
            o[0]  += pv * a.x;  o[1]  += pv * a.y;  o[2]  += pv * a.z;  o[3]  += pv * a.w;
            o[4]  += pv * bq.x; o[5]  += pv * bq.y; o[6]  += pv * bq.z; o[7]  += pv * bq.w;
            o[8]  += pv * c.x;  o[9]  += pv * c.y;  o[10] += pv * c.z;  o[11] += pv * c.w;
            o[12] += pv * e.x;  o[13] += pv * e.y;  o[14] += pv * e.z;  o[15] += pv * e.w;
        }
    }

    float scale = rmask[b * 8 + h] / l;
    float* dst = ctx + ((size_t)(b * SEQ + qglob) * DIM) + h * DK + c0;
    float4 w0 = { o[0]*scale,  o[1]*scale,  o[2]*scale,  o[3]*scale };
    float4 w1 = { o[4]*scale,  o[5]*scale,  o[6]*scale,  o[7]*scale };
    float4 w2 = { o[8]*scale,  o[9]*scale,  o[10]*scale, o[11]*scale };
    float4 w3 = { o[12]*scale, o[13]*scale, o[14]*scale, o[15]*scale };
    ((float4*)dst)[0] = w0; ((float4*)dst)[1] = w1;
    ((float4*)dst)[2] = w2; ((float4*)dst)[3] = w3;
}

// ---- row q==0: attn uniform 1/SEQ over ALL keys (pad_zero semantics) ----
__global__ void attn_row0(const float* __restrict__ vlin,
                          const float* __restrict__ rmask, float* __restrict__ ctx)
{
    int h = blockIdx.x, b = blockIdx.y;
    int d = threadIdx.x;   // 64
    float s = 0.f;
    size_t base = (size_t)b * SEQ * DIM + h * DK + d;
    for (int j = 0; j < SEQ; j++) s += vlin[base + (size_t)j * DIM];
    ctx[(size_t)(b * SEQ) * DIM + h * DK + d] = s * (1.0f / (float)SEQ) * rmask[b * 8 + h];
}

// ---- x = LN(x + y) ----
__global__ __launch_bounds__(256) void add_ln(
    float* __restrict__ x, const float* __restrict__ y,
    const float* __restrict__ g, const float* __restrict__ bta)
{
    __shared__ float redA[4], redB[4];
    int row = blockIdx.x, tid = threadIdx.x;
    size_t base = (size_t)row * DIM;
    float t0 = x[base + tid] + y[base + tid];
    float t1 = x[base + tid + 256] + y[base + tid + 256];
    float s = t0 + t1, sq = t0 * t0 + t1 * t1;
    for (int o = 32; o > 0; o >>= 1) { s += __shfl_down(s, o, 64); sq += __shfl_down(sq, o, 64); }
    int lane = tid & 63, wid = tid >> 6;
    if (lane == 0) { redA[wid] = s; redB[wid] = sq; }
    __syncthreads();
    float S1 = redA[0] + redA[1] + redA[2] + redA[3];
    float S2 = redB[0] + redB[1] + redB[2] + redB[3];
    float mu = S1 * (1.0f / (float)DIM);
    float var = S2 * (1.0f / (float)DIM) - mu * mu;
    float rstd = rsqrtf(var + 1e-5f);
    x[base + tid]       = g[tid]       * (t0 - mu) * rstd + bta[tid];
    x[base + tid + 256] = g[tid + 256] * (t1 - mu) * rstd + bta[tid + 256];
}

// ---------------- host side ----------------
extern "C" void kernel_launch(void* const* d_in, const int* in_sizes, int n_in,
                              void* d_out, int out_size, void* d_ws, size_t ws_size,
                              hipStream_t stream) {
    const float* qe   = (const float*)d_in[0];
    const float* ie   = (const float*)d_in[1];
    const float* wq   = (const float*)d_in[2];
    const float* bq   = (const float*)d_in[3];
    const float* wv   = (const float*)d_in[4];
    const float* bv   = (const float*)d_in[5];
    const float* wo   = (const float*)d_in[6];
    const float* bo   = (const float*)d_in[7];
    const float* wg   = (const float*)d_in[8];
    const float* ln1g = (const float*)d_in[9];
    const float* ln1b = (const float*)d_in[10];
    const float* fw1  = (const float*)d_in[11];
    const float* fb1  = (const float*)d_in[12];
    const float* fw2  = (const float*)d_in[13];
    const float* fb2  = (const float*)d_in[14];
    const float* ln2g = (const float*)d_in[15];
    const float* ln2b = (const float*)d_in[16];

    const size_t RD = (size_t)NROWS * DIM;
    float* ws    = (float*)d_ws;
    float* xbuf  = ws;
    float* ybuf  = xbuf + RD;
    float* qlin  = ybuf + RD;
    float* vbuf  = qlin + RD;
    float* ctxb  = vbuf + RD;
    float* hchk  = ctxb + RD;
    float* rmask = hchk + RD;
    float* proj  = vbuf;   // alias: vbuf dead after attn

    const size_t nBytes = RD * sizeof(float);
    hipMemcpyAsync(xbuf, qe, nBytes, hipMemcpyDeviceToDevice, stream);
    hipMemcpyAsync(ybuf, ie, nBytes, hipMemcpyDeviceToDevice, stream);

    auto run_gemm = [&](const float* A, const float* W, const float* bias, float* C,
                        int M, int N, int K, int lda, int ldw, int ldc, int relu, int accum) {
        dim3 g(N / 64, M / 64);
        gemm_bias<<<g, 256, 0, stream>>>(A, W, bias, C, K, lda, ldw, ldc, relu, accum);
    };

    auto run_block = [&](float* xq, const float* xv, int l, int maskf, int pos) {
        run_gemm(xq, wq + (size_t)l * DIM * DIM, bq + (size_t)l * DIM, qlin,
                 NROWS, DIM, DIM, DIM, DIM, DIM, 0, 0);
        run_gemm(xv, wv + (size_t)l * DIM * DIM, bv + (size_t)l * DIM, vbuf,
                 NROWS, DIM, DIM, DIM, DIM, DIM, 0, 0);
        init_rmask<<<1, 128, 0, stream>>>(rmask);
        router_kernel<<<NROWS / 256, 256, 0, stream>>>(qlin, wg + (size_t)l * DIM * 6, rmask);
        attn_flash<<<dim3(SEQ / 64, NH, BSZ), 256, 0, stream>>>(qlin, vbuf, rmask, ctxb, maskf);
        attn_row0<<<dim3(NH, BSZ), 64, 0, stream>>>(vbuf, rmask, ctxb);
        run_gemm(ctxb, wo + (size_t)l * DIM * DIM, bo + (size_t)l * DIM, proj,
                 NROWS, DIM, DIM, DIM, DIM, DIM, 0, 0);
        add_ln<<<NROWS, 256, 0, stream>>>(xq, proj, ln1g + (size_t)l * DIM, ln1b + (size_t)l * DIM);
        if (pos) {
            for (int c = 0; c < 4; c++) {
                run_gemm(xq, fw1 + (size_t)l * DIM * DFF2 + c * 512,
                         fb1 + (size_t)l * DFF2 + c * 512, hchk,
                         NROWS, 512, DIM, DIM, DFF2, 512, 1, 0);
                run_gemm(hchk, fw2 + (size_t)l * DFF2 * DIM + (size_t)c * 512 * DIM,
                         (c == 0) ? (fb2 + (size_t)l * DIM) : nullptr, proj,
                         NROWS, DIM, 512, 512, DIM, DIM, 0, (c == 0) ? 0 : 1);
            }
            add_ln<<<NROWS, 256, 0, stream>>>(xq, proj, ln2g + (size_t)l * DIM, ln2b + (size_t)l * DIM);
        }
    };

    run_block(ybuf, ybuf, 0, 1, 0);
    run_block(ybuf, ybuf, 1, 1, 0);
    run_block(xbuf, xbuf, 2, 1, 0);
    run_block(xbuf, ybuf, 3, 0, 1);
    run_block(xbuf, xbuf, 4, 1, 0);
    run_block(xbuf, ybuf, 5, 0, 1);

    hipMemcpyAsync(d_out, xbuf, nBytes, hipMemcpyDeviceToDevice, stream);
}

// Round 4
// 2217.942 us; speedup vs baseline: 5.9514x; 1.7547x over previous
//
#include <hip/hip_runtime.h>
#include <hip/hip_bf16.h>

#define BSZ 16
#define SEQ 512
#define DIM 512
#define NH 8
#define DK 64
#define NROWS (BSZ*SEQ)   // 8192
#define DFF2 2048

typedef unsigned short u16;
typedef u16   u16x8 __attribute__((ext_vector_type(8)));
typedef short s16x8 __attribute__((ext_vector_type(8)));
typedef float f32x4 __attribute__((ext_vector_type(4)));

__device__ __forceinline__ u16 f2b(float x) {
    union { float f; unsigned int u; } c; c.f = x;
    unsigned int r = c.u + 0x7fff + ((c.u >> 16) & 1);   // RNE
    return (u16)(r >> 16);
}

// ---- cast fp32 -> bf16 (vectorized, n must be /4) ----
__global__ __launch_bounds__(256) void cast_f2b4(const float* __restrict__ in,
                                                 u16* __restrict__ out, int n4) {
    int i = blockIdx.x * 256 + threadIdx.x;
    if (i >= n4) return;
    float4 v = ((const float4*)in)[i];
    ushort4 o; o.x = f2b(v.x); o.y = f2b(v.y); o.z = f2b(v.z); o.w = f2b(v.w);
    ((ushort4*)out)[i] = o;
}

// ---- transpose + cast: WT[z][N][K] (bf16) from W[layer0+z*lstride][K][N] (fp32) ----
__global__ __launch_bounds__(256) void transpose_cast(
    const float* __restrict__ W, u16* __restrict__ WT,
    int K, int N, int layer0, int lstride)
{
    __shared__ float t[32][33];
    int z = blockIdx.z;
    const float* Wz = W + (size_t)(layer0 + z * lstride) * K * N;
    u16* WTz = WT + (size_t)z * K * N;
    int k0 = blockIdx.x * 32, n0 = blockIdx.y * 32;
    int tx = threadIdx.x & 31, ty = threadIdx.x >> 5;
    for (int i = ty; i < 32; i += 8) t[i][tx] = Wz[(size_t)(k0 + i) * N + n0 + tx];
    __syncthreads();
    for (int i = ty; i < 32; i += 8) WTz[(size_t)(n0 + i) * K + k0 + tx] = f2b(t[tx][i]);
}

// ---- MFMA GEMM: C[M,N] = A[M,K](bf16) @ WT[N,K](bf16)^T + bias(fp32) ----
// 128x128 tile, BK=32, 4 waves each owning a 64x64 quadrant (4x4 16x16 frags).
template<int WRITE_BF16, int RELU>
__global__ __launch_bounds__(256) void gemm_mfma(
    const u16* __restrict__ A, const u16* __restrict__ WT,
    const float* __restrict__ bias, void* __restrict__ Cout,
    int M, int N, int K)
{
    __shared__ u16 As[128][48];   // 96B row stride
    __shared__ u16 Bs[128][48];
    int tid = threadIdx.x;
    int wave = tid >> 6, lane = tid & 63;
    int quad = lane >> 4, l16 = lane & 15;
    int n0 = blockIdx.x * 128, m0 = blockIdx.y * 128;
    int wrow = (wave & 1) * 64, wcol = (wave >> 1) * 64;

    int srow = tid >> 1, shalf = tid & 1;
    const u16* Ap = A  + (size_t)(m0 + srow) * K + shalf * 16;
    const u16* Bp = WT + (size_t)(n0 + srow) * K + shalf * 16;

    f32x4 acc[4][4];
    #pragma unroll
    for (int i = 0; i < 4; i++)
        #pragma unroll
        for (int j = 0; j < 4; j++) acc[i][j] = (f32x4){0.f, 0.f, 0.f, 0.f};

    for (int k0 = 0; k0 < K; k0 += 32) {
        u16x8 a0 = *(const u16x8*)(Ap + k0);
        u16x8 a1 = *(const u16x8*)(Ap + k0 + 8);
        u16x8 b0 = *(const u16x8*)(Bp + k0);
        u16x8 b1 = *(const u16x8*)(Bp + k0 + 8);
        __syncthreads();                       // prior iter's LDS reads done
        *(u16x8*)&As[srow][shalf * 16]     = a0;
        *(u16x8*)&As[srow][shalf * 16 + 8] = a1;
        *(u16x8*)&Bs[srow][shalf * 16]     = b0;
        *(u16x8*)&Bs[srow][shalf * 16 + 8] = b1;
        __syncthreads();                       // staging visible

        s16x8 af[4], bf[4];
        #pragma unroll
        for (int i = 0; i < 4; i++) {
            af[i] = *(s16x8*)&As[wrow + i * 16 + l16][quad * 8];
            bf[i] = *(s16x8*)&Bs[wcol + i * 16 + l16][quad * 8];
        }
        #pragma unroll
        for (int mi = 0; mi < 4; mi++)
            #pragma unroll
            for (int ni = 0; ni < 4; ni++)
                acc[mi][ni] = __builtin_amdgcn_mfma_f32_16x16x32_bf16(
                    af[mi], bf[ni], acc[mi][ni], 0, 0, 0);
    }

    #pragma unroll
    for (int ni = 0; ni < 4; ni++) {
        int cn = n0 + wcol + ni * 16 + l16;
        float bb = bias[cn];
        #pragma unroll
        for (int mi = 0; mi < 4; mi++) {
            int cm = m0 + wrow + mi * 16 + quad * 4;
            #pragma unroll
            for (int r = 0; r < 4; r++) {
                float v = acc[mi][ni][r] + bb;
                if (RELU) v = fmaxf(v, 0.f);
                if (WRITE_BF16) ((u16*)Cout)[(size_t)(cm + r) * N + cn] = f2b(v);
                else            ((float*)Cout)[(size_t)(cm + r) * N + cn] = v;
            }
        }
    }
}

// ---- router ----
__global__ void init_rmask(float* __restrict__ rmask) {
    int t = threadIdx.x;   // 128 = B*NH
    rmask[t] = ((t & 7) < 2) ? 1.0f : 0.0f;
}

__global__ __launch_bounds__(256) void router_kernel(
    const float* __restrict__ qlin, const float* __restrict__ wg,
    float* __restrict__ rmask)
{
    __shared__ float s_wg[DIM * 6];
    for (int i = threadIdx.x; i < DIM * 6; i += 256) s_wg[i] = wg[i];
    __syncthreads();
    int row = blockIdx.x * 256 + threadIdx.x;
    const float* xr = qlin + (size_t)row * DIM;
    float lg[6] = {0, 0, 0, 0, 0, 0};
    for (int d = 0; d < DIM; d++) {
        float x = xr[d];
        #pragma unroll
        for (int r = 0; r < 6; r++) lg[r] += x * s_wg[d * 6 + r];
    }
    float m = lg[0];
    #pragma unroll
    for (int r = 1; r < 6; r++) m = fmaxf(m, lg[r]);
    float s = 0.f;
    #pragma unroll
    for (int r = 0; r < 6; r++) { lg[r] = __expf(lg[r] - m); s += lg[r]; }
    float inv = 1.0f / s;
    #pragma unroll
    for (int r = 0; r < 6; r++) lg[r] *= inv;
    int i1 = 0; float v1 = lg[0];
    #pragma unroll
    for (int r = 1; r < 6; r++) if (lg[r] > v1) { v1 = lg[r]; i1 = r; }
    int i2 = -1; float v2 = -1.f;
    #pragma unroll
    for (int r = 0; r < 6; r++) if (r != i1 && lg[r] > v2) { v2 = lg[r]; i2 = r; }
    int b = row >> 9;
    atomicAdd(&rmask[b * 8 + 2 + i1], v1 * (1.0f / (float)SEQ));
    atomicAdd(&rmask[b * 8 + 2 + i2], v2 * (1.0f / (float)SEQ));
}

// ---- flash attention (unchanged from round 3) ----
__global__ __launch_bounds__(256) void attn_flash(
    const float* __restrict__ qlin, const float* __restrict__ vlin,
    const float* __restrict__ rmask, float* __restrict__ ctx, int mask_flag)
{
    __shared__ float s_q [64][68];
    __shared__ float s_kp[64][68];
    __shared__ float s_v [64][68];
    int qt = blockIdx.x, h = blockIdx.y, b = blockIdx.z;
    int tid = threadIdx.x;
    int lane = tid & 63;
    int wid = tid >> 6;
    int r  = wid * 16 + (lane >> 2);
    int c0 = (lane & 3) * 16;
    int lr = tid >> 2, lc = (tid & 3) * 16;
    int qglob = qt * 64 + r;

    {
        const float* src = qlin + ((size_t)(b * SEQ + qt * 64 + lr) * DIM) + h * DK + lc;
        float4 q0 = ((const float4*)src)[0], q1 = ((const float4*)src)[1];
        float4 q2 = ((const float4*)src)[2], q3 = ((const float4*)src)[3];
        *(float4*)&s_q[lr][lc]      = q0; *(float4*)&s_q[lr][lc + 4]  = q1;
        *(float4*)&s_q[lr][lc + 8]  = q2; *(float4*)&s_q[lr][lc + 12] = q3;
    }

    float o[16];
    #pragma unroll
    for (int i = 0; i < 16; i++) o[i] = 0.f;
    float m = -1e30f, l = 0.f;

    for (int jt = 0; jt <= qt; jt++) {
        const float* ksrc = qlin + ((size_t)(b * SEQ + jt * 64 + lr) * DIM) + h * DK + lc;
        const float* vsrc = vlin + ((size_t)(b * SEQ + jt * 64 + lr) * DIM) + h * DK + lc;
        float4 k0 = ((const float4*)ksrc)[0], k1 = ((const float4*)ksrc)[1];
        float4 k2 = ((const float4*)ksrc)[2], k3 = ((const float4*)ksrc)[3];
        float4 v0 = ((const float4*)vsrc)[0], v1 = ((const float4*)vsrc)[1];
        float4 v2 = ((const float4*)vsrc)[2], v3 = ((const float4*)vsrc)[3];
        __syncthreads();
        float kk[16] = {k0.x,k0.y,k0.z,k0.w, k1.x,k1.y,k1.z,k1.w,
                        k2.x,k2.y,k2.z,k2.w, k3.x,k3.y,k3.z,k3.w};
        #pragma unroll
        for (int i = 0; i < 16; i++) s_kp[lc + i][lr] = kk[i];
        *(float4*)&s_v[lr][lc]      = v0; *(float4*)&s_v[lr][lc + 4]  = v1;
        *(float4*)&s_v[lr][lc + 8]  = v2; *(float4*)&s_v[lr][lc + 12] = v3;
        __syncthreads();

        float sc[16];
        #pragma unroll
        for (int i = 0; i < 16; i++) sc[i] = 0.f;
        for (int d = 0; d < 64; d++) {
            float qv = s_q[r][d];
            const float4* kr = (const float4*)&s_kp[d][c0];
            float4 a = kr[0], bq = kr[1], c = kr[2], e = kr[3];
            sc[0]  += qv * a.x;  sc[1]  += qv * a.y;  sc[2]  += qv * a.z;  sc[3]  += qv * a.w;
            sc[4]  += qv * bq.x; sc[5]  += qv * bq.y; sc[6]  += qv * bq.z; sc[7]  += qv * bq.w;
            sc[8]  += qv * c.x;  sc[9]  += qv * c.y;  sc[10] += qv * c.z;  sc[11] += qv * c.w;
            sc[12] += qv * e.x;  sc[13] += qv * e.y;  sc[14] += qv * e.z;  sc[15] += qv * e.w;
        }
        if (jt == qt) {
            int bound = mask_flag ? qglob : (qglob - 1);
            #pragma unroll
            for (int i = 0; i < 16; i++) {
                int jg = jt * 64 + c0 + i;
                sc[i] = (jg <= bound) ? sc[i] * 0.125f : -1e30f;
            }
        } else {
            #pragma unroll
            for (int i = 0; i < 16; i++) sc[i] *= 0.125f;
        }
        float tmax = sc[0];
        #pragma unroll
        for (int i = 1; i < 16; i++) tmax = fmaxf(tmax, sc[i]);
        tmax = fmaxf(tmax, __shfl_xor(tmax, 1));
        tmax = fmaxf(tmax, __shfl_xor(tmax, 2));
        float mnew = fmaxf(m, tmax);
        float alpha = __expf(m - mnew);
        float p[16], tsum = 0.f;
        #pragma unroll
        for (int i = 0; i < 16; i++) { p[i] = __expf(sc[i] - mnew); tsum += p[i]; }
        tsum += __shfl_xor(tsum, 1);
        tsum += __shfl_xor(tsum, 2);
        l = l * alpha + tsum;
        m = mnew;
        #pragma unroll
        for (int i = 0; i < 16; i++) o[i] *= alpha;
        __syncthreads();
        #pragma unroll
        for (int i = 0; i < 16; i++) s_kp[r][c0 + i] = p[i];
        __syncthreads();

        for (int j = 0; j < 64; j++) {
            float pv = s_kp[r][j];
            const float4* vr = (const float4*)&s_v[j][c0];
            float4 a = vr[0], bq = vr[1], c = vr[2], e = vr[3];
            o[0]  += pv * a.x;  o[1]  += pv * a.y;  o[2]  += pv * a.z;  o[3]  += pv * a.w;
            o[4]  += pv * bq.x; o[5]  += pv * bq.y; o[6]  += pv * bq.z; o[7]  += pv * bq.w;
            o[8]  += pv * c.x;  o[9]  += pv * c.y;  o[10] += pv * c.z;  o[11] += pv * c.w;
            o[12] += pv * e.x;  o[13] += pv * e.y;  o[14] += pv * e.z;  o[15] += pv * e.w;
        }
    }

    float scale = rmask[b * 8 + h] / l;
    float* dst = ctx + ((size_t)(b * SEQ + qglob) * DIM) + h * DK + c0;
    float4 w0 = { o[0]*scale,  o[1]*scale,  o[2]*scale,  o[3]*scale };
    float4 w1 = { o[4]*scale,  o[5]*scale,  o[6]*scale,  o[7]*scale };
    float4 w2 = { o[8]*scale,  o[9]*scale,  o[10]*scale, o[11]*scale };
    float4 w3 = { o[12]*scale, o[13]*scale, o[14]*scale, o[15]*scale };
    ((float4*)dst)[0] = w0; ((float4*)dst)[1] = w1;
    ((float4*)dst)[2] = w2; ((float4*)dst)[3] = w3;
}

__global__ void attn_row0(const float* __restrict__ vlin,
                          const float* __restrict__ rmask, float* __restrict__ ctx)
{
    int h = blockIdx.x, b = blockIdx.y;
    int d = threadIdx.x;
    float s = 0.f;
    size_t base = (size_t)b * SEQ * DIM + h * DK + d;
    for (int j = 0; j < SEQ; j++) s += vlin[base + (size_t)j * DIM];
    ctx[(size_t)(b * SEQ) * DIM + h * DK + d] = s * (1.0f / (float)SEQ) * rmask[b * 8 + h];
}

// ---- x = LN(x + y) ----
__global__ __launch_bounds__(256) void add_ln(
    float* __restrict__ x, const float* __restrict__ y,
    const float* __restrict__ g, const float* __restrict__ bta)
{
    __shared__ float redA[4], redB[4];
    int row = blockIdx.x, tid = threadIdx.x;
    size_t base = (size_t)row * DIM;
    float t0 = x[base + tid] + y[base + tid];
    float t1 = x[base + tid + 256] + y[base + tid + 256];
    float s = t0 + t1, sq = t0 * t0 + t1 * t1;
    for (int o = 32; o > 0; o >>= 1) { s += __shfl_down(s, o, 64); sq += __shfl_down(sq, o, 64); }
    int lane = tid & 63, wid = tid >> 6;
    if (lane == 0) { redA[wid] = s; redB[wid] = sq; }
    __syncthreads();
    float S1 = redA[0] + redA[1] + redA[2] + redA[3];
    float S2 = redB[0] + redB[1] + redB[2] + redB[3];
    float mu = S1 * (1.0f / (float)DIM);
    float var = S2 * (1.0f / (float)DIM) - mu * mu;
    float rstd = rsqrtf(var + 1e-5f);
    x[base + tid]       = g[tid]       * (t0 - mu) * rstd + bta[tid];
    x[base + tid + 256] = g[tid + 256] * (t1 - mu) * rstd + bta[tid + 256];
}

// ---------------- host side ----------------
extern "C" void kernel_launch(void* const* d_in, const int* in_sizes, int n_in,
                              void* d_out, int out_size, void* d_ws, size_t ws_size,
                              hipStream_t stream) {
    const float* qe   = (const float*)d_in[0];
    const float* ie   = (const float*)d_in[1];
    const float* wq   = (const float*)d_in[2];
    const float* bq   = (const float*)d_in[3];
    const float* wv   = (const float*)d_in[4];
    const float* bv   = (const float*)d_in[5];
    const float* wo   = (const float*)d_in[6];
    const float* bo   = (const float*)d_in[7];
    const float* wg   = (const float*)d_in[8];
    const float* ln1g = (const float*)d_in[9];
    const float* ln1b = (const float*)d_in[10];
    const float* fw1  = (const float*)d_in[11];
    const float* fb1  = (const float*)d_in[12];
    const float* fw2  = (const float*)d_in[13];
    const float* fb2  = (const float*)d_in[14];
    const float* ln2g = (const float*)d_in[15];
    const float* ln2b = (const float*)d_in[16];

    const size_t RD = (size_t)NROWS * DIM;     // 4,194,304
    float* ws    = (float*)d_ws;
    float* xbuf  = ws;
    float* ybuf  = ws + RD;
    float* vbuf  = ws + 2 * RD;
    float* qlin  = ws + 3 * RD;
    float* ctxb  = ws + 4 * RD;
    float* proj  = vbuf;                       // alias (vbuf dead after attn)
    u16*   hid   = (u16*)qlin;                 // 8192x2048 bf16 over qlin+ctxb

    u16* b16   = (u16*)(ws + 5 * RD);
    u16* actA  = b16;                  b16 += RD;                 // 8192x512 bf16
    u16* wqT   = b16;                  b16 += 6 * (size_t)DIM * DIM;
    u16* wvT   = b16;                  b16 += 6 * (size_t)DIM * DIM;
    u16* woT   = b16;                  b16 += 6 * (size_t)DIM * DIM;
    u16* fw1T  = b16;                  b16 += 2 * (size_t)DIM * DFF2;
    u16* fw2T  = b16;                  b16 += 2 * (size_t)DIM * DFF2;
    float* rmask = (float*)b16;

    const size_t nBytes = RD * sizeof(float);
    hipMemcpyAsync(xbuf, qe, nBytes, hipMemcpyDeviceToDevice, stream);
    hipMemcpyAsync(ybuf, ie, nBytes, hipMemcpyDeviceToDevice, stream);

    // weight prep: transpose + cast to bf16 WT[N][K]
    transpose_cast<<<dim3(16, 16, 6), 256, 0, stream>>>(wq, wqT, DIM, DIM, 0, 1);
    transpose_cast<<<dim3(16, 16, 6), 256, 0, stream>>>(wv, wvT, DIM, DIM, 0, 1);
    transpose_cast<<<dim3(16, 16, 6), 256, 0, stream>>>(wo, woT, DIM, DIM, 0, 1);
    transpose_cast<<<dim3(16, 64, 2), 256, 0, stream>>>(fw1, fw1T, DIM, DFF2, 3, 2);
    transpose_cast<<<dim3(64, 16, 2), 256, 0, stream>>>(fw2, fw2T, DFF2, DIM, 3, 2);

    auto cast_act = [&](const float* src) {
        cast_f2b4<<<(int)(RD / 4 / 256), 256, 0, stream>>>(src, actA, (int)(RD / 4));
    };
    auto mm = [&](const u16* A, const u16* WT, const float* bias, void* C,
                  int M, int N, int K, int bf16relu) {
        dim3 g(N / 128, M / 128);
        if (bf16relu) gemm_mfma<1, 1><<<g, 256, 0, stream>>>(A, WT, bias, C, M, N, K);
        else          gemm_mfma<0, 0><<<g, 256, 0, stream>>>(A, WT, bias, C, M, N, K);
    };

    auto run_block = [&](float* xq, const float* xv, int l, int maskf, int pos) {
        size_t lDD = (size_t)l * DIM * DIM, lD = (size_t)l * DIM;
        if (xv != xq) {
            cast_act(xv);
            mm(actA, wvT + lDD, bv + lD, vbuf, NROWS, DIM, DIM, 0);
            cast_act(xq);
            mm(actA, wqT + lDD, bq + lD, qlin, NROWS, DIM, DIM, 0);
        } else {
            cast_act(xq);
            mm(actA, wvT + lDD, bv + lD, vbuf, NROWS, DIM, DIM, 0);
            mm(actA, wqT + lDD, bq + lD, qlin, NROWS, DIM, DIM, 0);
        }
        init_rmask<<<1, 128, 0, stream>>>(rmask);
        router_kernel<<<NROWS / 256, 256, 0, stream>>>(qlin, wg + (size_t)l * DIM * 6, rmask);
        attn_flash<<<dim3(SEQ / 64, NH, BSZ), 256, 0, stream>>>(qlin, vbuf, rmask, ctxb, maskf);
        attn_row0<<<dim3(NH, BSZ), 64, 0, stream>>>(vbuf, rmask, ctxb);
        cast_act(ctxb);
        mm(actA, woT + lDD, bo + lD, proj, NROWS, DIM, DIM, 0);
        add_ln<<<NROWS, 256, 0, stream>>>(xq, proj, ln1g + lD, ln1b + lD);
        if (pos) {
            int slot = (l - 3) / 2;
            cast_act(xq);
            mm(actA, fw1T + (size_t)slot * DIM * DFF2, fb1 + (size_t)l * DFF2,
               hid, NROWS, DFF2, DIM, 1);
            mm(hid, fw2T + (size_t)slot * DIM * DFF2, fb2 + lD,
               proj, NROWS, DIM, DFF2, 0);
            add_ln<<<NROWS, 256, 0, stream>>>(xq, proj, ln2g + lD, ln2b + lD);
        }
    };

    run_block(ybuf, ybuf, 0, 1, 0);
    run_block(ybuf, ybuf, 1, 1, 0);
    run_block(xbuf, xbuf, 2, 1, 0);
    run_block(xbuf, ybuf, 3, 0, 1);
    run_block(xbuf, xbuf, 4, 1, 0);
    run_block(xbuf, ybuf, 5, 0, 1);

    hipMemcpyAsync(d_out, xbuf, nBytes, hipMemcpyDeviceToDevice, stream);
}

// Round 6
// 1420.027 us; speedup vs baseline: 9.2954x; 1.5619x over previous
//
#include <hip/hip_runtime.h>
#include <hip/hip_bf16.h>

#define BSZ 16
#define SEQ 512
#define DIM 512
#define NH 8
#define DK 64
#define NROWS (BSZ*SEQ)   // 8192
#define DFF2 2048

typedef unsigned short u16;
typedef u16   u16x8 __attribute__((ext_vector_type(8)));
typedef short s16x8 __attribute__((ext_vector_type(8)));
typedef float f32x4 __attribute__((ext_vector_type(4)));

__device__ __forceinline__ u16 f2b(float x) {
    union { float f; unsigned int u; } c; c.f = x;
    unsigned int r = c.u + 0x7fff + ((c.u >> 16) & 1);   // RNE
    return (u16)(r >> 16);
}
__device__ __forceinline__ float b2f(u16 u) {
    union { unsigned int i; float f; } c; c.i = ((unsigned int)u) << 16; return c.f;
}

// ---- cast fp32 -> bf16 ----
__global__ __launch_bounds__(256) void cast_f2b4(const float* __restrict__ in,
                                                 u16* __restrict__ out, int n4) {
    int i = blockIdx.x * 256 + threadIdx.x;
    if (i >= n4) return;
    float4 v = ((const float4*)in)[i];
    ushort4 o; o.x = f2b(v.x); o.y = f2b(v.y); o.z = f2b(v.z); o.w = f2b(v.w);
    ((ushort4*)out)[i] = o;
}

// ---- transpose + cast: WT[z][N][K] (bf16) from W[layer0+z*lstride][K][N] (fp32) ----
__global__ __launch_bounds__(256) void transpose_cast(
    const float* __restrict__ W, u16* __restrict__ WT,
    int K, int N, int layer0, int lstride)
{
    __shared__ float t[32][33];
    int z = blockIdx.z;
    const float* Wz = W + (size_t)(layer0 + z * lstride) * K * N;
    u16* WTz = WT + (size_t)z * K * N;
    int k0 = blockIdx.x * 32, n0 = blockIdx.y * 32;
    int tx = threadIdx.x & 31, ty = threadIdx.x >> 5;
    for (int i = ty; i < 32; i += 8) t[i][tx] = Wz[(size_t)(k0 + i) * N + n0 + tx];
    __syncthreads();
    for (int i = ty; i < 32; i += 8) WTz[(size_t)(n0 + i) * K + k0 + tx] = f2b(t[tx][i]);
}

// ---- MFMA GEMM: C[M,N] = A[M,K](bf16, lda) @ WT[N,K](bf16, ldw)^T + bias + (ACCUM?C:0) ----
template<int WRITE_BF16, int RELU, int ACCUM>
__global__ __launch_bounds__(256) void gemm_mfma(
    const u16* __restrict__ A, const u16* __restrict__ WT,
    const float* __restrict__ bias, void* __restrict__ Cout,
    int K, int lda, int ldw, int ldc)
{
    __shared__ u16 As[128][48];
    __shared__ u16 Bs[128][48];
    int tid = threadIdx.x;
    int wave = tid >> 6, lane = tid & 63;
    int quad = lane >> 4, l16 = lane & 15;
    int n0 = blockIdx.x * 128, m0 = blockIdx.y * 128;
    int wrow = (wave & 1) * 64, wcol = (wave >> 1) * 64;

    int srow = tid >> 1, shalf = tid & 1;
    const u16* Ap = A  + (size_t)(m0 + srow) * lda + shalf * 16;
    const u16* Bp = WT + (size_t)(n0 + srow) * ldw + shalf * 16;

    f32x4 acc[4][4];
    #pragma unroll
    for (int i = 0; i < 4; i++)
        #pragma unroll
        for (int j = 0; j < 4; j++) acc[i][j] = (f32x4){0.f, 0.f, 0.f, 0.f};

    for (int k0 = 0; k0 < K; k0 += 32) {
        u16x8 a0 = *(const u16x8*)(Ap + k0);
        u16x8 a1 = *(const u16x8*)(Ap + k0 + 8);
        u16x8 b0 = *(const u16x8*)(Bp + k0);
        u16x8 b1 = *(const u16x8*)(Bp + k0 + 8);
        __syncthreads();
        *(u16x8*)&As[srow][shalf * 16]     = a0;
        *(u16x8*)&As[srow][shalf * 16 + 8] = a1;
        *(u16x8*)&Bs[srow][shalf * 16]     = b0;
        *(u16x8*)&Bs[srow][shalf * 16 + 8] = b1;
        __syncthreads();

        s16x8 af[4], bf[4];
        #pragma unroll
        for (int i = 0; i < 4; i++) {
            af[i] = *(s16x8*)&As[wrow + i * 16 + l16][quad * 8];
            bf[i] = *(s16x8*)&Bs[wcol + i * 16 + l16][quad * 8];
        }
        #pragma unroll
        for (int mi = 0; mi < 4; mi++)
            #pragma unroll
            for (int ni = 0; ni < 4; ni++)
                acc[mi][ni] = __builtin_amdgcn_mfma_f32_16x16x32_bf16(
                    af[mi], bf[ni], acc[mi][ni], 0, 0, 0);
    }

    #pragma unroll
    for (int ni = 0; ni < 4; ni++) {
        int cn = n0 + wcol + ni * 16 + l16;
        float bb = bias ? bias[cn] : 0.f;
        #pragma unroll
        for (int mi = 0; mi < 4; mi++) {
            int cm = m0 + wrow + mi * 16 + quad * 4;
            #pragma unroll
            for (int r = 0; r < 4; r++) {
                size_t off = (size_t)(cm + r) * ldc + cn;
                float v = acc[mi][ni][r] + bb;
                if (ACCUM) v += ((float*)Cout)[off];
                if (RELU) v = fmaxf(v, 0.f);
                if (WRITE_BF16) ((u16*)Cout)[off] = f2b(v);
                else            ((float*)Cout)[off] = v;
            }
        }
    }
}

// ---- router (reads bf16 qlin) ----
__global__ void init_rmask(float* __restrict__ rmask) {
    int t = threadIdx.x;   // 128 = B*NH
    rmask[t] = ((t & 7) < 2) ? 1.0f : 0.0f;
}

__global__ __launch_bounds__(256) void router_kernel(
    const u16* __restrict__ qlin, const float* __restrict__ wg,
    float* __restrict__ rmask)
{
    __shared__ float s_wg[DIM * 6];
    for (int i = threadIdx.x; i < DIM * 6; i += 256) s_wg[i] = wg[i];
    __syncthreads();
    int row = blockIdx.x * 256 + threadIdx.x;
    const u16* xr = qlin + (size_t)row * DIM;
    float lg[6] = {0, 0, 0, 0, 0, 0};
    for (int d8 = 0; d8 < DIM / 8; d8++) {
        u16x8 v = *(const u16x8*)(xr + d8 * 8);
        #pragma unroll
        for (int j = 0; j < 8; j++) {
            float x = b2f(v[j]);
            #pragma unroll
            for (int r = 0; r < 6; r++) lg[r] += x * s_wg[(d8 * 8 + j) * 6 + r];
        }
    }
    float m = lg[0];
    #pragma unroll
    for (int r = 1; r < 6; r++) m = fmaxf(m, lg[r]);
    float s = 0.f;
    #pragma unroll
    for (int r = 0; r < 6; r++) { lg[r] = __expf(lg[r] - m); s += lg[r]; }
    float inv = 1.0f / s;
    #pragma unroll
    for (int r = 0; r < 6; r++) lg[r] *= inv;
    int i1 = 0; float v1 = lg[0];
    #pragma unroll
    for (int r = 1; r < 6; r++) if (lg[r] > v1) { v1 = lg[r]; i1 = r; }
    int i2 = -1; float v2 = -1.f;
    #pragma unroll
    for (int r = 0; r < 6; r++) if (r != i1 && lg[r] > v2) { v2 = lg[r]; i2 = r; }
    int b = row >> 9;
    atomicAdd(&rmask[b * 8 + 2 + i1], v1 * (1.0f / (float)SEQ));
    atomicAdd(&rmask[b * 8 + 2 + i2], v2 * (1.0f / (float)SEQ));
}

// ---- MFMA flash attention. qlin/vlin bf16, ctx bf16. kq_same. ----
__global__ __launch_bounds__(256) void attn_flash(
    const u16* __restrict__ qlin, const u16* __restrict__ vlin,
    const float* __restrict__ rmask, u16* __restrict__ ctx, int mask_flag)
{
    __shared__ u16 s_q [64][72];
    __shared__ u16 s_k [64][72];
    __shared__ u16 s_vt[64][72];   // V transposed: [d][j]
    __shared__ u16 s_p [64][72];
    int qt = blockIdx.x, h = blockIdx.y, b = blockIdx.z;
    int tid = threadIdx.x;
    int wave = tid >> 6, lane = tid & 63;
    int quad = lane >> 4, l16 = lane & 15;
    int lr = tid >> 2, lc = (tid & 3) * 16;

    {
        const u16* src = qlin + (size_t)(b * SEQ + qt * 64 + lr) * DIM + h * DK + lc;
        *(u16x8*)&s_q[lr][lc]     = *(const u16x8*)src;
        *(u16x8*)&s_q[lr][lc + 8] = *(const u16x8*)(src + 8);
    }

    f32x4 acc_o[4];
    #pragma unroll
    for (int i = 0; i < 4; i++) acc_o[i] = (f32x4){0.f, 0.f, 0.f, 0.f};
    float m_i[4] = {-1e30f, -1e30f, -1e30f, -1e30f};
    float l_i[4] = {0.f, 0.f, 0.f, 0.f};

    for (int jt = 0; jt <= qt; jt++) {
        const u16* ksrc = qlin + (size_t)(b * SEQ + jt * 64 + lr) * DIM + h * DK + lc;
        const u16* vsrc = vlin + (size_t)(b * SEQ + jt * 64 + lr) * DIM + h * DK + lc;
        u16x8 k0 = *(const u16x8*)ksrc, k1 = *(const u16x8*)(ksrc + 8);
        u16x8 v0 = *(const u16x8*)vsrc, v1 = *(const u16x8*)(vsrc + 8);
        __syncthreads();
        *(u16x8*)&s_k[lr][lc]     = k0;
        *(u16x8*)&s_k[lr][lc + 8] = k1;
        #pragma unroll
        for (int i = 0; i < 8; i++) s_vt[lc + i][lr] = v0[i];
        #pragma unroll
        for (int i = 0; i < 8; i++) s_vt[lc + 8 + i][lr] = v1[i];
        __syncthreads();

        f32x4 acc_s[4];
        #pragma unroll
        for (int i = 0; i < 4; i++) acc_s[i] = (f32x4){0.f, 0.f, 0.f, 0.f};
        #pragma unroll
        for (int ks = 0; ks < 2; ks++) {
            s16x8 a = *(s16x8*)&s_q[wave * 16 + l16][ks * 32 + quad * 8];
            #pragma unroll
            for (int nf = 0; nf < 4; nf++) {
                s16x8 bb = *(s16x8*)&s_k[nf * 16 + l16][ks * 32 + quad * 8];
                acc_s[nf] = __builtin_amdgcn_mfma_f32_16x16x32_bf16(a, bb, acc_s[nf], 0, 0, 0);
            }
        }

        int qg0 = qt * 64 + wave * 16 + quad * 4;
        float sc[4][4];
        #pragma unroll
        for (int nf = 0; nf < 4; nf++) {
            int jg = jt * 64 + nf * 16 + l16;
            #pragma unroll
            for (int r = 0; r < 4; r++) {
                float v = acc_s[nf][r] * 0.125f;
                if (jt == qt) {
                    int bound = mask_flag ? (qg0 + r) : (qg0 + r - 1);
                    if (jg > bound) v = -1e30f;
                }
                sc[nf][r] = v;
            }
        }
        float tmax[4];
        #pragma unroll
        for (int r = 0; r < 4; r++) {
            float t = fmaxf(fmaxf(sc[0][r], sc[1][r]), fmaxf(sc[2][r], sc[3][r]));
            #pragma unroll
            for (int o = 1; o < 16; o <<= 1) t = fmaxf(t, __shfl_xor(t, o));
            tmax[r] = t;
        }
        float p[4][4];
        #pragma unroll
        for (int r = 0; r < 4; r++) {
            float mnew = fmaxf(m_i[r], tmax[r]);
            float alpha = __expf(m_i[r] - mnew);
            float su = 0.f;
            #pragma unroll
            for (int nf = 0; nf < 4; nf++) { p[nf][r] = __expf(sc[nf][r] - mnew); su += p[nf][r]; }
            #pragma unroll
            for (int o = 1; o < 16; o <<= 1) su += __shfl_xor(su, o);
            l_i[r] = l_i[r] * alpha + su;
            m_i[r] = mnew;
            #pragma unroll
            for (int nf = 0; nf < 4; nf++) acc_o[nf][r] *= alpha;
        }
        #pragma unroll
        for (int nf = 0; nf < 4; nf++)
            #pragma unroll
            for (int r = 0; r < 4; r++)
                s_p[wave * 16 + quad * 4 + r][nf * 16 + l16] = f2b(p[nf][r]);

        #pragma unroll
        for (int ks = 0; ks < 2; ks++) {
            s16x8 a = *(s16x8*)&s_p[wave * 16 + l16][ks * 32 + quad * 8];
            #pragma unroll
            for (int nf = 0; nf < 4; nf++) {
                s16x8 bb = *(s16x8*)&s_vt[nf * 16 + l16][ks * 32 + quad * 8];
                acc_o[nf] = __builtin_amdgcn_mfma_f32_16x16x32_bf16(a, bb, acc_o[nf], 0, 0, 0);
            }
        }
    }

    float rm = rmask[b * 8 + h];
    int qrow = qt * 64 + wave * 16 + quad * 4;
    #pragma unroll
    for (int r = 0; r < 4; r++) {
        float scale = rm / l_i[r];
        u16* dst = ctx + (size_t)(b * SEQ + qrow + r) * DIM + h * DK;
        #pragma unroll
        for (int nf = 0; nf < 4; nf++)
            dst[nf * 16 + l16] = f2b(acc_o[nf][r] * scale);
    }
}

// ---- row q==0: uniform 1/SEQ over ALL keys (pad_zero) ----
__global__ void attn_row0(const u16* __restrict__ vlin,
                          const float* __restrict__ rmask, u16* __restrict__ ctx)
{
    int h = blockIdx.x, b = blockIdx.y;
    int d = threadIdx.x;
    float s = 0.f;
    size_t base = (size_t)b * SEQ * DIM + h * DK + d;
    for (int j = 0; j < SEQ; j++) s += b2f(vlin[base + (size_t)j * DIM]);
    ctx[(size_t)(b * SEQ) * DIM + h * DK + d] = f2b(s * (1.0f / (float)SEQ) * rmask[b * 8 + h]);
}

// ---- x = LN(x + y) ----
__global__ __launch_bounds__(256) void add_ln(
    float* __restrict__ x, const float* __restrict__ y,
    const float* __restrict__ g, const float* __restrict__ bta)
{
    __shared__ float redA[4], redB[4];
    int row = blockIdx.x, tid = threadIdx.x;
    size_t base = (size_t)row * DIM;
    float t0 = x[base + tid] + y[base + tid];
    float t1 = x[base + tid + 256] + y[base + tid + 256];
    float s = t0 + t1, sq = t0 * t0 + t1 * t1;
    for (int o = 32; o > 0; o >>= 1) { s += __shfl_down(s, o, 64); sq += __shfl_down(sq, o, 64); }
    int lane = tid & 63, wid = tid >> 6;
    if (lane == 0) { redA[wid] = s; redB[wid] = sq; }
    __syncthreads();
    float S1 = redA[0] + redA[1] + redA[2] + redA[3];
    float S2 = redB[0] + redB[1] + redB[2] + redB[3];
    float mu = S1 * (1.0f / (float)DIM);
    float var = S2 * (1.0f / (float)DIM) - mu * mu;
    float rstd = rsqrtf(var + 1e-5f);
    x[base + tid]       = g[tid]       * (t0 - mu) * rstd + bta[tid];
    x[base + tid + 256] = g[tid + 256] * (t1 - mu) * rstd + bta[tid + 256];
}

// ---------------- host side ----------------
extern "C" void kernel_launch(void* const* d_in, const int* in_sizes, int n_in,
                              void* d_out, int out_size, void* d_ws, size_t ws_size,
                              hipStream_t stream) {
    const float* qe   = (const float*)d_in[0];
    const float* ie   = (const float*)d_in[1];
    const float* wq   = (const float*)d_in[2];
    const float* bq   = (const float*)d_in[3];
    const float* wv   = (const float*)d_in[4];
    const float* bv   = (const float*)d_in[5];
    const float* wo   = (const float*)d_in[6];
    const float* bo   = (const float*)d_in[7];
    const float* wg   = (const float*)d_in[8];
    const float* ln1g = (const float*)d_in[9];
    const float* ln1b = (const float*)d_in[10];
    const float* fw1  = (const float*)d_in[11];
    const float* fb1  = (const float*)d_in[12];
    const float* fw2  = (const float*)d_in[13];
    const float* fb2  = (const float*)d_in[14];
    const float* ln2g = (const float*)d_in[15];
    const float* ln2b = (const float*)d_in[16];

    const size_t RD = (size_t)NROWS * DIM;     // 4,194,304
    float* ws    = (float*)d_ws;
    float* xbuf  = ws;
    float* ybuf  = ws + RD;
    float* proj  = ws + 2 * RD;

    u16* b16    = (u16*)(ws + 3 * RD);
    u16* actA   = b16;                 b16 += RD;
    u16* qlin16 = b16;                 b16 += RD;
    u16* vbuf16 = b16;                 b16 += RD;
    // FFN hidden processed in 2 chunks of 1024 cols: NROWS*1024 u16 = 16 MiB,
    // exactly the size of qlin16+vbuf16 (both dead during FFN). No spill.
    u16* hid    = qlin16;
    u16* wqT    = b16;                 b16 += 6 * (size_t)DIM * DIM;
    u16* wvT    = b16;                 b16 += 6 * (size_t)DIM * DIM;
    u16* woT    = b16;                 b16 += 6 * (size_t)DIM * DIM;
    u16* fw1T   = b16;                 b16 += 2 * (size_t)DIM * DFF2;
    u16* fw2T   = b16;                 b16 += 2 * (size_t)DIM * DFF2;
    float* rmask = (float*)b16;

    const size_t nBytes = RD * sizeof(float);
    hipMemcpyAsync(xbuf, qe, nBytes, hipMemcpyDeviceToDevice, stream);
    hipMemcpyAsync(ybuf, ie, nBytes, hipMemcpyDeviceToDevice, stream);

    transpose_cast<<<dim3(16, 16, 6), 256, 0, stream>>>(wq, wqT, DIM, DIM, 0, 1);
    transpose_cast<<<dim3(16, 16, 6), 256, 0, stream>>>(wv, wvT, DIM, DIM, 0, 1);
    transpose_cast<<<dim3(16, 16, 6), 256, 0, stream>>>(wo, woT, DIM, DIM, 0, 1);
    transpose_cast<<<dim3(16, 64, 2), 256, 0, stream>>>(fw1, fw1T, DIM, DFF2, 3, 2);
    transpose_cast<<<dim3(64, 16, 2), 256, 0, stream>>>(fw2, fw2T, DFF2, DIM, 3, 2);

    auto cast_act = [&](const float* src) {
        cast_f2b4<<<(int)(RD / 4 / 256), 256, 0, stream>>>(src, actA, (int)(RD / 4));
    };

    auto run_block = [&](float* xq, const float* xv, int l, int maskf, int pos) {
        size_t lDD = (size_t)l * DIM * DIM, lD = (size_t)l * DIM;
        if (xv != xq) {
            cast_act(xv);
            gemm_mfma<1, 0, 0><<<dim3(4, 64), 256, 0, stream>>>(
                actA, wvT + lDD, bv + lD, vbuf16, DIM, DIM, DIM, DIM);
            cast_act(xq);
            gemm_mfma<1, 0, 0><<<dim3(4, 64), 256, 0, stream>>>(
                actA, wqT + lDD, bq + lD, qlin16, DIM, DIM, DIM, DIM);
        } else {
            cast_act(xq);
            gemm_mfma<1, 0, 0><<<dim3(4, 64), 256, 0, stream>>>(
                actA, wvT + lDD, bv + lD, vbuf16, DIM, DIM, DIM, DIM);
            gemm_mfma<1, 0, 0><<<dim3(4, 64), 256, 0, stream>>>(
                actA, wqT + lDD, bq + lD, qlin16, DIM, DIM, DIM, DIM);
        }
        init_rmask<<<1, 128, 0, stream>>>(rmask);
        router_kernel<<<NROWS / 256, 256, 0, stream>>>(qlin16, wg + (size_t)l * DIM * 6, rmask);
        attn_flash<<<dim3(SEQ / 64, NH, BSZ), 256, 0, stream>>>(qlin16, vbuf16, rmask, actA, maskf);
        attn_row0<<<dim3(NH, BSZ), 64, 0, stream>>>(vbuf16, rmask, actA);
        gemm_mfma<0, 0, 0><<<dim3(4, 64), 256, 0, stream>>>(
            actA, woT + lDD, bo + lD, proj, DIM, DIM, DIM, DIM);
        add_ln<<<NROWS, 256, 0, stream>>>(xq, proj, ln1g + lD, ln1b + lD);
        if (pos) {
            int slot = (l - 3) / 2;
            cast_act(xq);
            // FFN in 2 chunks of 1024 hidden cols (hid = 16 MiB, fits overlay)
            for (int c = 0; c < 2; c++) {
                gemm_mfma<1, 1, 0><<<dim3(8, 64), 256, 0, stream>>>(
                    actA, fw1T + (size_t)slot * DIM * DFF2 + (size_t)c * 1024 * DIM,
                    fb1 + (size_t)l * DFF2 + c * 1024, hid,
                    DIM, DIM, DIM, 1024);
                if (c == 0)
                    gemm_mfma<0, 0, 0><<<dim3(4, 64), 256, 0, stream>>>(
                        hid, fw2T + (size_t)slot * DIM * DFF2 + c * 1024,
                        fb2 + lD, proj, 1024, 1024, DFF2, DIM);
                else
                    gemm_mfma<0, 0, 1><<<dim3(4, 64), 256, 0, stream>>>(
                        hid, fw2T + (size_t)slot * DIM * DFF2 + c * 1024,
                        nullptr, proj, 1024, 1024, DFF2, DIM);
            }
            add_ln<<<NROWS, 256, 0, stream>>>(xq, proj, ln2g + lD, ln2b + lD);
        }
    };

    run_block(ybuf, ybuf, 0, 1, 0);
    run_block(ybuf, ybuf, 1, 1, 0);
    run_block(xbuf, xbuf, 2, 1, 0);
    run_block(xbuf, ybuf, 3, 0, 1);
    run_block(xbuf, xbuf, 4, 1, 0);
    run_block(xbuf, ybuf, 5, 0, 1);

    hipMemcpyAsync(d_out, xbuf, nBytes, hipMemcpyDeviceToDevice, stream);
}

// Round 7
// 1234.070 us; speedup vs baseline: 10.6961x; 1.1507x over previous
//
#include <hip/hip_runtime.h>
#include <hip/hip_bf16.h>

#define BSZ 16
#define SEQ 512
#define DIM 512
#define NH 8
#define DK 64
#define NROWS (BSZ*SEQ)   // 8192
#define DFF2 2048

typedef unsigned short u16;
typedef u16   u16x8 __attribute__((ext_vector_type(8)));
typedef short s16x8 __attribute__((ext_vector_type(8)));
typedef float f32x4 __attribute__((ext_vector_type(4)));

__device__ __forceinline__ u16 f2b(float x) {
    union { float f; unsigned int u; } c; c.f = x;
    unsigned int r = c.u + 0x7fff + ((c.u >> 16) & 1);   // RNE
    return (u16)(r >> 16);
}
__device__ __forceinline__ float b2f(u16 u) {
    union { unsigned int i; float f; } c; c.i = ((unsigned int)u) << 16; return c.f;
}

// async global->LDS, 16B per lane. LDS dest = wave-uniform base + lane*16.
__device__ __forceinline__ void gld16(const u16* g, u16* l) {
    __builtin_amdgcn_global_load_lds(
        (const __attribute__((address_space(1))) unsigned int*)(unsigned long long)g,
        (__attribute__((address_space(3))) unsigned int*)(unsigned int)(unsigned long long)l,
        16, 0, 0);
}

// ---- cast fp32 -> bf16 ----
__global__ __launch_bounds__(256) void cast_f2b4(const float* __restrict__ in,
                                                 u16* __restrict__ out, int n4) {
    int i = blockIdx.x * 256 + threadIdx.x;
    if (i >= n4) return;
    float4 v = ((const float4*)in)[i];
    ushort4 o; o.x = f2b(v.x); o.y = f2b(v.y); o.z = f2b(v.z); o.w = f2b(v.w);
    ((ushort4*)out)[i] = o;
}

// ---- transpose + cast weights: dest[z][N][K](bf16) from W[layer0+z*lstride][K][N](fp32) ----
__global__ __launch_bounds__(256) void transpose_cast(
    const float* __restrict__ W, u16* __restrict__ WT,
    int K, int N, int layer0, int lstride, size_t dstride)
{
    __shared__ float t[32][33];
    int z = blockIdx.z;
    const float* Wz = W + (size_t)(layer0 + z * lstride) * K * N;
    u16* WTz = WT + (size_t)z * dstride;
    int k0 = blockIdx.x * 32, n0 = blockIdx.y * 32;
    int tx = threadIdx.x & 31, ty = threadIdx.x >> 5;
    for (int i = ty; i < 32; i += 8) t[i][tx] = Wz[(size_t)(k0 + i) * N + n0 + tx];
    __syncthreads();
    for (int i = ty; i < 32; i += 8) WTz[(size_t)(n0 + i) * K + k0 + tx] = f2b(t[tx][i]);
}

// ---- m97-style MFMA GEMM. C[M,N] = A[M,K] @ WT[N,K]^T + bias. 128x128, BK=32. ----
// SPLIT: columns >= nsplit use Av/bias2/C2 (for fused q|v with different A streams).
template<int WRITE_BF16, int RELU, int ACCUM, int SPLIT>
__global__ __launch_bounds__(256) void gemm2(
    const u16* __restrict__ Aq, const u16* __restrict__ Av,
    const u16* __restrict__ WT,
    const float* __restrict__ bias1, const float* __restrict__ bias2,
    void* __restrict__ C1, void* __restrict__ C2,
    int K, int lda, int ldw, int ldc, int nsplit)
{
    __shared__ __attribute__((aligned(16))) u16 As[128 * 32];
    __shared__ __attribute__((aligned(16))) u16 Bs[128 * 32];
    int tid = threadIdx.x;
    int wave = tid >> 6, lane = tid & 63;
    int quad = lane >> 4, l16 = lane & 15;
    int n0 = blockIdx.x * 128, m0 = blockIdx.y * 128;
    int wrow = (wave & 1) * 64, wcol = (wave >> 1) * 64;
    bool isv = SPLIT && (n0 >= nsplit);
    const u16* A = isv ? Av : Aq;

    // staging: wave w covers rows [w*32, w*32+32) of each tile; 2 insts of 16 rows
    int sr = wave * 32 + (lane >> 2);
    int sc = (lane & 3) * 8;
    const u16* gA0 = A  + (size_t)(m0 + sr) * lda + sc;
    const u16* gA1 = gA0 + (size_t)16 * lda;
    const u16* gB0 = WT + (size_t)(n0 + sr) * ldw + sc;
    const u16* gB1 = gB0 + (size_t)16 * ldw;
    u16* lA0 = As + (wave * 32) * 32;
    u16* lA1 = As + (wave * 32 + 16) * 32;
    u16* lB0 = Bs + (wave * 32) * 32;
    u16* lB1 = Bs + (wave * 32 + 16) * 32;

    f32x4 acc[4][4];
    #pragma unroll
    for (int i = 0; i < 4; i++)
        #pragma unroll
        for (int j = 0; j < 4; j++) acc[i][j] = (f32x4){0.f, 0.f, 0.f, 0.f};

    for (int k0 = 0; k0 < K; k0 += 32) {
        __syncthreads();                 // prior iter's frag reads done
        gld16(gA0 + k0, lA0);
        gld16(gA1 + k0, lA1);
        gld16(gB0 + k0, lB0);
        gld16(gB1 + k0, lB1);
        __syncthreads();                 // drains vmcnt -> staging visible

        s16x8 af[4], bf[4];
        #pragma unroll
        for (int i = 0; i < 4; i++) {
            af[i] = *(s16x8*)&As[(wrow + i * 16 + l16) * 32 + quad * 8];
            bf[i] = *(s16x8*)&Bs[(wcol + i * 16 + l16) * 32 + quad * 8];
        }
        #pragma unroll
        for (int mi = 0; mi < 4; mi++)
            #pragma unroll
            for (int ni = 0; ni < 4; ni++)
                acc[mi][ni] = __builtin_amdgcn_mfma_f32_16x16x32_bf16(
                    af[mi], bf[ni], acc[mi][ni], 0, 0, 0);
    }

    const float* bias = isv ? bias2 : bias1;
    void* C = isv ? C2 : C1;
    int nb = n0 - (isv ? nsplit : 0);
    #pragma unroll
    for (int ni = 0; ni < 4; ni++) {
        int cn = nb + wcol + ni * 16 + l16;
        float bb = bias ? bias[cn] : 0.f;
        #pragma unroll
        for (int mi = 0; mi < 4; mi++) {
            int cm = m0 + wrow + mi * 16 + quad * 4;
            #pragma unroll
            for (int r = 0; r < 4; r++) {
                size_t off = (size_t)(cm + r) * ldc + cn;
                float v = acc[mi][ni][r] + bb;
                if (ACCUM) v += ((float*)C)[off];
                if (RELU) v = fmaxf(v, 0.f);
                if (WRITE_BF16) ((u16*)C)[off] = f2b(v);
                else            ((float*)C)[off] = v;
            }
        }
    }
}

// ---- rmask init for all 6 layers: [l][b][h], shared heads = 1, routed = 0 ----
__global__ void init_rmask6(float* __restrict__ r) {
    int t = blockIdx.x * 256 + threadIdx.x;
    if (t < 6 * 128) r[t] = ((t & 7) < 2) ? 1.0f : 0.0f;
}

__global__ __launch_bounds__(256) void router_kernel(
    const u16* __restrict__ qlin, const float* __restrict__ wg,
    float* __restrict__ rmask)
{
    __shared__ float s_wg[DIM * 6];
    for (int i = threadIdx.x; i < DIM * 6; i += 256) s_wg[i] = wg[i];
    __syncthreads();
    int row = blockIdx.x * 256 + threadIdx.x;
    const u16* xr = qlin + (size_t)row * DIM;
    float lg[6] = {0, 0, 0, 0, 0, 0};
    for (int d8 = 0; d8 < DIM / 8; d8++) {
        u16x8 v = *(const u16x8*)(xr + d8 * 8);
        #pragma unroll
        for (int j = 0; j < 8; j++) {
            float x = b2f(v[j]);
            #pragma unroll
            for (int r = 0; r < 6; r++) lg[r] += x * s_wg[(d8 * 8 + j) * 6 + r];
        }
    }
    float m = lg[0];
    #pragma unroll
    for (int r = 1; r < 6; r++) m = fmaxf(m, lg[r]);
    float s = 0.f;
    #pragma unroll
    for (int r = 0; r < 6; r++) { lg[r] = __expf(lg[r] - m); s += lg[r]; }
    float inv = 1.0f / s;
    #pragma unroll
    for (int r = 0; r < 6; r++) lg[r] *= inv;
    int i1 = 0; float v1 = lg[0];
    #pragma unroll
    for (int r = 1; r < 6; r++) if (lg[r] > v1) { v1 = lg[r]; i1 = r; }
    int i2 = -1; float v2 = -1.f;
    #pragma unroll
    for (int r = 0; r < 6; r++) if (r != i1 && lg[r] > v2) { v2 = lg[r]; i2 = r; }
    int b = row >> 9;
    atomicAdd(&rmask[b * 8 + 2 + i1], v1 * (1.0f / (float)SEQ));
    atomicAdd(&rmask[b * 8 + 2 + i2], v2 * (1.0f / (float)SEQ));
}

// ---- per-layer V transpose: vT[b][h][d][j] from v[(b,j)][h*64+d] ----
__global__ __launch_bounds__(256) void transpose_v(
    const u16* __restrict__ v, u16* __restrict__ vT)
{
    __shared__ u16 t[64][72];
    int jt = blockIdx.x, bh = blockIdx.y;
    int b = bh >> 3, h = bh & 7;
    int tid = threadIdx.x;
    int lr = tid >> 2, lc = (tid & 3) * 16;
    const u16* src = v + (size_t)(b * SEQ + jt * 64 + lr) * DIM + h * DK + lc;
    *(u16x8*)&t[lr][lc]     = *(const u16x8*)src;
    *(u16x8*)&t[lr][lc + 8] = *(const u16x8*)(src + 8);
    __syncthreads();
    u16x8 o0, o1;
    #pragma unroll
    for (int i = 0; i < 8; i++) o0[i] = t[lc + i][lr];
    #pragma unroll
    for (int i = 0; i < 8; i++) o1[i] = t[lc + 8 + i][lr];
    u16* dst = vT + ((size_t)bh * DK + lr) * SEQ + jt * 64 + lc;
    *(u16x8*)dst       = o0;
    *(u16x8*)(dst + 8) = o1;
}

// ---- MFMA flash attention. Q/K from qlin16, V from vT (pre-transposed). ----
__global__ __launch_bounds__(256) void attn_flash(
    const u16* __restrict__ qlin, const u16* __restrict__ vT,
    const float* __restrict__ rmask, u16* __restrict__ ctx, int mask_flag)
{
    __shared__ u16 s_q [64][72];
    __shared__ u16 s_k [64][72];
    __shared__ u16 s_vt[64][72];   // [d][j]
    __shared__ u16 s_p [64][72];
    int qt = blockIdx.x, h = blockIdx.y, b = blockIdx.z;
    int tid = threadIdx.x;
    int wave = tid >> 6, lane = tid & 63;
    int quad = lane >> 4, l16 = lane & 15;
    int lr = tid >> 2, lc = (tid & 3) * 16;

    {
        const u16* src = qlin + (size_t)(b * SEQ + qt * 64 + lr) * DIM + h * DK + lc;
        *(u16x8*)&s_q[lr][lc]     = *(const u16x8*)src;
        *(u16x8*)&s_q[lr][lc + 8] = *(const u16x8*)(src + 8);
    }

    f32x4 acc_o[4];
    #pragma unroll
    for (int i = 0; i < 4; i++) acc_o[i] = (f32x4){0.f, 0.f, 0.f, 0.f};
    float m_i[4] = {-1e30f, -1e30f, -1e30f, -1e30f};
    float l_i[4] = {0.f, 0.f, 0.f, 0.f};

    for (int jt = 0; jt <= qt; jt++) {
        const u16* ksrc = qlin + (size_t)(b * SEQ + jt * 64 + lr) * DIM + h * DK + lc;
        const u16* vtsrc = vT + ((size_t)(b * NH + h) * DK + lr) * SEQ + jt * 64 + lc;
        u16x8 k0 = *(const u16x8*)ksrc,  k1 = *(const u16x8*)(ksrc + 8);
        u16x8 v0 = *(const u16x8*)vtsrc, v1 = *(const u16x8*)(vtsrc + 8);
        __syncthreads();
        *(u16x8*)&s_k[lr][lc]      = k0;
        *(u16x8*)&s_k[lr][lc + 8]  = k1;
        *(u16x8*)&s_vt[lr][lc]     = v0;
        *(u16x8*)&s_vt[lr][lc + 8] = v1;
        __syncthreads();

        f32x4 acc_s[4];
        #pragma unroll
        for (int i = 0; i < 4; i++) acc_s[i] = (f32x4){0.f, 0.f, 0.f, 0.f};
        #pragma unroll
        for (int ks = 0; ks < 2; ks++) {
            s16x8 a = *(s16x8*)&s_q[wave * 16 + l16][ks * 32 + quad * 8];
            #pragma unroll
            for (int nf = 0; nf < 4; nf++) {
                s16x8 bb = *(s16x8*)&s_k[nf * 16 + l16][ks * 32 + quad * 8];
                acc_s[nf] = __builtin_amdgcn_mfma_f32_16x16x32_bf16(a, bb, acc_s[nf], 0, 0, 0);
            }
        }

        int qg0 = qt * 64 + wave * 16 + quad * 4;
        float sc[4][4];
        #pragma unroll
        for (int nf = 0; nf < 4; nf++) {
            int jg = jt * 64 + nf * 16 + l16;
            #pragma unroll
            for (int r = 0; r < 4; r++) {
                float v = acc_s[nf][r] * 0.125f;
                if (jt == qt) {
                    int bound = mask_flag ? (qg0 + r) : (qg0 + r - 1);
                    if (jg > bound) v = -1e30f;
                }
                sc[nf][r] = v;
            }
        }
        float tmax[4];
        #pragma unroll
        for (int r = 0; r < 4; r++) {
            float t = fmaxf(fmaxf(sc[0][r], sc[1][r]), fmaxf(sc[2][r], sc[3][r]));
            #pragma unroll
            for (int o = 1; o < 16; o <<= 1) t = fmaxf(t, __shfl_xor(t, o));
            tmax[r] = t;
        }
        float p[4][4];
        #pragma unroll
        for (int r = 0; r < 4; r++) {
            float mnew = fmaxf(m_i[r], tmax[r]);
            float alpha = __expf(m_i[r] - mnew);
            float su = 0.f;
            #pragma unroll
            for (int nf = 0; nf < 4; nf++) { p[nf][r] = __expf(sc[nf][r] - mnew); su += p[nf][r]; }
            #pragma unroll
            for (int o = 1; o < 16; o <<= 1) su += __shfl_xor(su, o);
            l_i[r] = l_i[r] * alpha + su;
            m_i[r] = mnew;
            #pragma unroll
            for (int nf = 0; nf < 4; nf++) acc_o[nf][r] *= alpha;
        }
        #pragma unroll
        for (int nf = 0; nf < 4; nf++)
            #pragma unroll
            for (int r = 0; r < 4; r++)
                s_p[wave * 16 + quad * 4 + r][nf * 16 + l16] = f2b(p[nf][r]);

        #pragma unroll
        for (int ks = 0; ks < 2; ks++) {
            s16x8 a = *(s16x8*)&s_p[wave * 16 + l16][ks * 32 + quad * 8];
            #pragma unroll
            for (int nf = 0; nf < 4; nf++) {
                s16x8 bb = *(s16x8*)&s_vt[nf * 16 + l16][ks * 32 + quad * 8];
                acc_o[nf] = __builtin_amdgcn_mfma_f32_16x16x32_bf16(a, bb, acc_o[nf], 0, 0, 0);
            }
        }
    }

    float rm = rmask[b * 8 + h];
    int qrow = qt * 64 + wave * 16 + quad * 4;
    #pragma unroll
    for (int r = 0; r < 4; r++) {
        float scale = rm / l_i[r];
        u16* dst = ctx + (size_t)(b * SEQ + qrow + r) * DIM + h * DK;
        #pragma unroll
        for (int nf = 0; nf < 4; nf++)
            dst[nf * 16 + l16] = f2b(acc_o[nf][r] * scale);
    }
}

// ---- row q==0: uniform 1/SEQ over ALL keys; coalesced reads from vT ----
__global__ __launch_bounds__(256) void attn_row0(
    const u16* __restrict__ vT, const float* __restrict__ rmask, u16* __restrict__ ctx)
{
    int bh = blockIdx.x;
    int b = bh >> 3, h = bh & 7;
    int d = threadIdx.x >> 2, seg = threadIdx.x & 3;
    const u16* src = vT + ((size_t)bh * DK + d) * SEQ + seg * 128;
    float s = 0.f;
    for (int i = 0; i < 16; i++) {
        u16x8 v = *(const u16x8*)(src + i * 8);
        #pragma unroll
        for (int j = 0; j < 8; j++) s += b2f(v[j]);
    }
    s += __shfl_down(s, 1);
    s += __shfl_down(s, 2);
    if (seg == 0)
        ctx[(size_t)(b * SEQ) * DIM + h * DK + d] =
            f2b(s * (1.0f / (float)SEQ) * rmask[b * 8 + h]);
}

// ---- x = LN(x + y), also emit bf16 copy ----
__global__ __launch_bounds__(256) void add_ln_c(
    float* __restrict__ x, const float* __restrict__ y,
    const float* __restrict__ g, const float* __restrict__ bta,
    u16* __restrict__ out16)
{
    __shared__ float redA[4], redB[4];
    int row = blockIdx.x, tid = threadIdx.x;
    size_t base = (size_t)row * DIM;
    float t0 = x[base + tid] + y[base + tid];
    float t1 = x[base + tid + 256] + y[base + tid + 256];
    float s = t0 + t1, sq = t0 * t0 + t1 * t1;
    for (int o = 32; o > 0; o >>= 1) { s += __shfl_down(s, o, 64); sq += __shfl_down(sq, o, 64); }
    int lane = tid & 63, wid = tid >> 6;
    if (lane == 0) { redA[wid] = s; redB[wid] = sq; }
    __syncthreads();
    float S1 = redA[0] + redA[1] + redA[2] + redA[3];
    float S2 = redB[0] + redB[1] + redB[2] + redB[3];
    float mu = S1 * (1.0f / (float)DIM);
    float var = S2 * (1.0f / (float)DIM) - mu * mu;
    float rstd = rsqrtf(var + 1e-5f);
    float o0 = g[tid]       * (t0 - mu) * rstd + bta[tid];
    float o1 = g[tid + 256] * (t1 - mu) * rstd + bta[tid + 256];
    x[base + tid]       = o0;
    x[base + tid + 256] = o1;
    out16[base + tid]       = f2b(o0);
    out16[base + tid + 256] = f2b(o1);
}

// ---------------- host side ----------------
extern "C" void kernel_launch(void* const* d_in, const int* in_sizes, int n_in,
                              void* d_out, int out_size, void* d_ws, size_t ws_size,
                              hipStream_t stream) {
    const float* qe   = (const float*)d_in[0];
    const float* ie   = (const float*)d_in[1];
    const float* wq   = (const float*)d_in[2];
    const float* bq   = (const float*)d_in[3];
    const float* wv   = (const float*)d_in[4];
    const float* bv   = (const float*)d_in[5];
    const float* wo   = (const float*)d_in[6];
    const float* bo   = (const float*)d_in[7];
    const float* wg   = (const float*)d_in[8];
    const float* ln1g = (const float*)d_in[9];
    const float* ln1b = (const float*)d_in[10];
    const float* fw1  = (const float*)d_in[11];
    const float* fb1  = (const float*)d_in[12];
    const float* fw2  = (const float*)d_in[13];
    const float* fb2  = (const float*)d_in[14];
    const float* ln2g = (const float*)d_in[15];
    const float* ln2b = (const float*)d_in[16];

    const size_t RD = (size_t)NROWS * DIM;     // 4,194,304
    float* ws   = (float*)d_ws;
    float* xbuf = ws;                          // question residual (fp32)
    float* ybuf = ws + RD;                     // knowledge residual (fp32)

    u16* b16    = (u16*)(ws + 2 * RD);
    u16* x16    = b16;                 b16 += RD;
    u16* y16    = b16;                 b16 += RD;
    u16* ctx16  = b16;                 b16 += RD;
    u16* qlin16 = b16;                 b16 += RD;
    u16* vbuf16 = b16;                 b16 += RD;
    u16* vT     = b16;                 b16 += RD;
    u16* hid    = ctx16;                        // 16 MiB overlay: ctx16+qlin16 (dead in FFN)
    float* proj = (float*)vbuf16;               // 16 MiB overlay: vbuf16+vT (dead after attn)
    u16* wqvT   = b16;                 b16 += 6 * (size_t)1024 * 512;
    u16* woT    = b16;                 b16 += 6 * (size_t)512 * 512;
    u16* fw1T   = b16;                 b16 += 2 * (size_t)DFF2 * 512;
    u16* fw2T   = b16;                 b16 += 2 * (size_t)512 * DFF2;
    float* rmask6 = (float*)b16;                // 6*128 floats

    const size_t nBytes = RD * sizeof(float);
    hipMemcpyAsync(xbuf, qe, nBytes, hipMemcpyDeviceToDevice, stream);
    hipMemcpyAsync(ybuf, ie, nBytes, hipMemcpyDeviceToDevice, stream);
    cast_f2b4<<<(int)(RD / 4 / 256), 256, 0, stream>>>(qe, x16, (int)(RD / 4));
    cast_f2b4<<<(int)(RD / 4 / 256), 256, 0, stream>>>(ie, y16, (int)(RD / 4));

    transpose_cast<<<dim3(16, 16, 6), 256, 0, stream>>>(wq, wqvT,             512, 512, 0, 1, (size_t)1024 * 512);
    transpose_cast<<<dim3(16, 16, 6), 256, 0, stream>>>(wv, wqvT + 512 * 512, 512, 512, 0, 1, (size_t)1024 * 512);
    transpose_cast<<<dim3(16, 16, 6), 256, 0, stream>>>(wo, woT,              512, 512, 0, 1, (size_t)512 * 512);
    transpose_cast<<<dim3(16, 64, 2), 256, 0, stream>>>(fw1, fw1T, 512, DFF2, 3, 2, (size_t)DFF2 * 512);
    transpose_cast<<<dim3(64, 16, 2), 256, 0, stream>>>(fw2, fw2T, DFF2, 512, 3, 2, (size_t)512 * DFF2);
    init_rmask6<<<3, 256, 0, stream>>>(rmask6);

    const int BIG = 1 << 30;
    auto run_block = [&](float* xr, u16* xq16, const u16* xv16, int l, int maskf, int pos) {
        size_t lD = (size_t)l * DIM;
        float* rm = rmask6 + l * 128;
        gemm2<1, 0, 0, 1><<<dim3(8, 64), 256, 0, stream>>>(
            xq16, xv16, wqvT + (size_t)l * 1024 * 512, bq + lD, bv + lD,
            qlin16, vbuf16, 512, 512, 512, 512, 512);
        transpose_v<<<dim3(8, 128), 256, 0, stream>>>(vbuf16, vT);
        router_kernel<<<NROWS / 256, 256, 0, stream>>>(qlin16, wg + (size_t)l * DIM * 6, rm);
        attn_flash<<<dim3(SEQ / 64, NH, BSZ), 256, 0, stream>>>(qlin16, vT, rm, ctx16, maskf);
        attn_row0<<<128, 256, 0, stream>>>(vT, rm, ctx16);
        gemm2<0, 0, 0, 0><<<dim3(4, 64), 256, 0, stream>>>(
            ctx16, ctx16, woT + (size_t)l * 512 * 512, bo + lD, nullptr,
            proj, nullptr, 512, 512, 512, 512, BIG);
        add_ln_c<<<NROWS, 256, 0, stream>>>(xr, proj, ln1g + lD, ln1b + lD, xq16);
        if (pos) {
            int slot = (l - 3) / 2;
            for (int c = 0; c < 2; c++) {
                gemm2<1, 1, 0, 0><<<dim3(8, 64), 256, 0, stream>>>(
                    xq16, xq16,
                    fw1T + (size_t)slot * DFF2 * 512 + (size_t)c * 1024 * 512,
                    fb1 + (size_t)l * DFF2 + c * 1024, nullptr,
                    hid, nullptr, 512, 512, 512, 1024, BIG);
                if (c == 0)
                    gemm2<0, 0, 0, 0><<<dim3(4, 64), 256, 0, stream>>>(
                        hid, hid, fw2T + (size_t)slot * 512 * DFF2,
                        fb2 + lD, nullptr, proj, nullptr, 1024, 1024, DFF2, 512, BIG);
                else
                    gemm2<0, 0, 1, 0><<<dim3(4, 64), 256, 0, stream>>>(
                        hid, hid, fw2T + (size_t)slot * 512 * DFF2 + 1024,
                        nullptr, nullptr, proj, nullptr, 1024, 1024, DFF2, 512, BIG);
            }
            add_ln_c<<<NROWS, 256, 0, stream>>>(xr, proj, ln2g + lD, ln2b + lD, xq16);
        }
    };

    run_block(ybuf, y16, y16, 0, 1, 0);
    run_block(ybuf, y16, y16, 1, 1, 0);
    run_block(xbuf, x16, x16, 2, 1, 0);
    run_block(xbuf, x16, y16, 3, 0, 1);
    run_block(xbuf, x16, x16, 4, 1, 0);
    run_block(xbuf, x16, y16, 5, 0, 1);

    hipMemcpyAsync(d_out, xbuf, nBytes, hipMemcpyDeviceToDevice, stream);
}